// Round 5
// baseline (342.457 us; speedup 1.0000x reference)
//
#include <hip/hip_runtime.h>

#define S_LEN 4096
#define NT 512
#define PER 8
#define RANK 8
#define AP 4160   // padded LDS array size (max transpose addr 4151)
#define TWO_PI 6.2831853071795864769f

__device__ __forceinline__ void cmul(float& xr, float& xi, float cr, float ci){
    float tr = xr*cr - xi*ci;
    xi = xr*ci + xi*cr;
    xr = tr;
}

// 4-point DFT, in place. SIGN=-1 forward (W=e^{-i}), SIGN=+1 inverse.
template<int SIGN>
__device__ __forceinline__ void dft4(float& ar,float& ai,float& br,float& bi,
                                     float& cr,float& ci,float& dr,float& di){
    float Ar=ar+cr, Ai=ai+ci;
    float Br=ar-cr, Bi=ai-ci;
    float Cr=br+dr, Ci=bi+di;
    float Dr, Di;
    if (SIGN < 0){ Dr = bi-di; Di = dr-br; }   // -i*(b-d)
    else         { Dr = di-bi; Di = br-dr; }   // +i*(b-d)
    ar=Ar+Cr; ai=Ai+Ci;
    br=Br+Dr; bi=Bi+Di;
    cr=Ar-Cr; ci=Ai-Ci;
    dr=Br-Dr; di=Bi-Di;
}

// 8-point DFT in registers, natural-order in AND out (even/odd radix-2 split).
template<int SIGN>
__device__ __forceinline__ void dft8(float ur[8], float ui[8]){
    const float h = 0.70710678118654752f;
    float er0=ur[0], ei0=ui[0], er1=ur[2], ei1=ui[2];
    float er2=ur[4], ei2=ui[4], er3=ur[6], ei3=ui[6];
    float fr0=ur[1], fi0=ui[1], fr1=ur[3], fi1=ui[3];
    float fr2=ur[5], fi2=ui[5], fr3=ur[7], fi3=ui[7];
    dft4<SIGN>(er0,ei0, er1,ei1, er2,ei2, er3,ei3);   // E = DFT4(x0,x2,x4,x6)
    dft4<SIGN>(fr0,fi0, fr1,fi1, fr2,fi2, fr3,fi3);   // O = DFT4(x1,x3,x5,x7)
    // O[k] *= W8^k
    {   const float c =  h, s_ = (SIGN<0) ? -h : h;
        cmul(fr1, fi1, c, s_); }
    {   float tr = fr2, ti = fi2;
        if (SIGN < 0){ fr2 =  ti; fi2 = -tr; }   // *(-i)
        else         { fr2 = -ti; fi2 =  tr; }   // *(+i)
    }
    {   const float c = -h, s_ = (SIGN<0) ? -h : h;
        cmul(fr3, fi3, c, s_); }
    ur[0]=er0+fr0; ui[0]=ei0+fi0;
    ur[1]=er1+fr1; ui[1]=ei1+fi1;
    ur[2]=er2+fr2; ui[2]=ei2+fi2;
    ur[3]=er3+fr3; ui[3]=ei3+fi3;
    ur[4]=er0-fr0; ui[4]=ei0-fi0;
    ur[5]=er1-fr1; ui[5]=ei1-fi1;
    ur[6]=er2-fr2; ui[6]=ei2-fi2;
    ur[7]=er3-fr3; ui[7]=ei3-fi3;
}

// multiply u[m] by exp(SIGN * i * theta * m), m = 0..7 (iterative powers)
template<int SIGN>
__device__ __forceinline__ void twiddle8(float ur[8], float ui[8], float theta){
    float s, c;
    __sincosf(theta, &s, &c);
    const float wi = (SIGN < 0) ? -s : s;
    const float wr = c;
    float pr = wr, pi = wi;      // w^1
    cmul(ur[1], ui[1], pr, pi);
#pragma unroll
    for (int m=2;m<8;m++){
        float nr = pr*wr - pi*wi;
        pi = pr*wi + pi*wr;
        pr = nr;
        cmul(ur[m], ui[m], pr, pi);
    }
}

// 4096 = 8*8*8*8, n = n1 + 8n2 + 64n3 + 512n4, k = e1 + 8e2 + 64e3 + 512e4.
// Round r DFTs over n_{5-r}; twiddles W_{8^r}^{digit * k_so_far}.
// LDS layouts are digit-reversed so every round's READ is linear:
//   A[n1+8n2 + 64e1 + 512n3]           (write: 2-way, free; read: t+512m)
//   B[n1 + 8e1 + 64e2 + 520n2]         (write: 2-way via pad 520; read: t+520m)
//   C[(e1+8e2) + 64e3 + 520n1]         (write: 2-way via pad 520; read: t+520m)
//   z linear [t + 512e4]
//
// VGPR/occupancy rule MEASURED over r2-r4 on this chip/toolchain:
//   compiler cap = 256/min_waves_per_EU; HW waves/SIMD = 256/VGPR.
//   (512,8)->alloc 32 (spilled: true peak ~48); (512,4)->alloc 64 -> 4 waves
//   /SIMD = 43% occ. Strategy: LOWER the true peak (p/q accum split, 16 accum
//   per pass) then request (512,5) -> cap ~51 > peak ~40 -> 5 waves, no spill.

__global__ __launch_bounds__(NT, 5) void recip_mixer(
    const float* __restrict__ x,
    const float* __restrict__ Ur, const float* __restrict__ Ui,
    const float* __restrict__ Vr, const float* __restrict__ Vi,
    const float* __restrict__ Wr, const float* __restrict__ Wi,
    const float* __restrict__ P1w, const float* __restrict__ P1b,
    const float* __restrict__ P2w, const float* __restrict__ P2b,
    const float* __restrict__ alphap,
    float* __restrict__ out)
{
    __shared__ float sre[AP], sim[AP];
    __shared__ float red[256];
    __shared__ float hid[RANK];
    __shared__ float gam[2 * RANK];

    const int t    = threadIdx.x;
    const int row  = blockIdx.x;
    const int lane = t & 63;
    const int wid  = t >> 6;

    float ur[8], ui[8];

    // ================= forward FFT: natural in -> natural k out =================
    {
        // round 1: t = n1+8n2+64n3; DFT over n4 (global reads coalesced)
        const float* xrow = x + (size_t)row * S_LEN;
#pragma unroll
        for (int c=0;c<8;c++){ ur[c] = xrow[t + 512*c]; ui[c] = 0.0f; }
        dft8<-1>(ur, ui);
        const int baseA = (t & 63) + 512 * (t >> 6);
#pragma unroll
        for (int e=0;e<8;e++){ sre[baseA + 64*e] = ur[e]; sim[baseA + 64*e] = ui[e]; }
    }
    __syncthreads();
    {
        // round 2: t = (n1+8n2) + 64e1; read A linear, twiddle W_64^{n3 e1}, DFT over n3
#pragma unroll
        for (int m=0;m<8;m++){ ur[m] = sre[t + 512*m]; ui[m] = sim[t + 512*m]; }
        twiddle8<-1>(ur, ui, TWO_PI * (float)(t >> 6) * (1.0f/64.0f));
        dft8<-1>(ur, ui);
        __syncthreads();   // all of A consumed before B overwrites
        const int baseB = (t & 7) + 8*(t >> 6) + 520*((t >> 3) & 7);
#pragma unroll
        for (int e=0;e<8;e++){ sre[baseB + 64*e] = ur[e]; sim[baseB + 64*e] = ui[e]; }
    }
    __syncthreads();
    {
        // round 3: t = n1 + 8e1 + 64e2; read B linear, twiddle W_512^{n2 (e1+8e2)}, DFT over n2
#pragma unroll
        for (int m=0;m<8;m++){ ur[m] = sre[t + 520*m]; ui[m] = sim[t + 520*m]; }
        twiddle8<-1>(ur, ui, TWO_PI * (float)(t >> 3) * (1.0f/512.0f));
        dft8<-1>(ur, ui);
        __syncthreads();   // B consumed before C overwrites
        const int baseC = (t >> 3) + 520*(t & 7);
#pragma unroll
        for (int e=0;e<8;e++){ sre[baseC + 64*e] = ur[e]; sim[baseC + 64*e] = ui[e]; }
    }
    __syncthreads();
    {
        // round 4: t = e1+8e2+64e3 = k mod 512; read C linear, twiddle W_4096^{n1 t}, DFT over n1
#pragma unroll
        for (int m=0;m<8;m++){ ur[m] = sre[t + 520*m]; ui[m] = sim[t + 520*m]; }
        twiddle8<-1>(ur, ui, TWO_PI * (float)t * (1.0f/4096.0f));
        dft8<-1>(ur, ui);
        __syncthreads();   // C consumed before z overwrites
        // write spectrum linear: z[t + 512*e4]
#pragma unroll
        for (int e=0;e<8;e++){ sre[t + 512*e] = ur[e]; sim[t + 512*e] = ui[e]; }
    }
    __syncthreads();

    // ================= middle phase (z in sre/sim linear) =====
    // phase 1: hidden = relu(P1w @ [Re z ; Im z] + P1b)
    {
        float h[RANK];
#pragma unroll
        for (int r = 0; r < RANK; r++) h[r] = 0.0f;
        for (int i = 0; i < PER; i++) {
            int k = t + NT * i;
            float zr = sre[k], zi = sim[k];
#pragma unroll
            for (int r = 0; r < RANK; r++) {
                h[r] += zr * P1w[r * (2 * S_LEN) + k]
                      + zi * P1w[r * (2 * S_LEN) + S_LEN + k];
            }
        }
#pragma unroll
        for (int r = 0; r < RANK; r++) {
#pragma unroll
            for (int off = 32; off > 0; off >>= 1)
                h[r] += __shfl_xor(h[r], off, 64);
        }
        if (lane == 0) {
#pragma unroll
            for (int r = 0; r < RANK; r++) red[wid * RANK + r] = h[r];
        }
        __syncthreads();
        if (t < RANK) {
            float v = 0.0f;
#pragma unroll
            for (int w = 0; w < 8; w++) v += red[w * RANK + t];
            hid[t] = fmaxf(v + P1b[t], 0.0f);
        }
        __syncthreads();
    }

    // phase 2a: per-k gain, scale z in LDS. NO accumulators live here (~36 peak).
    // Each thread touches only its own k slots, so no barrier needed afterward.
    {
        float hh[RANK];
#pragma unroll
        for (int r = 0; r < RANK; r++) hh[r] = hid[r];
        const float alpha = alphap[0];

        for (int i = 0; i < PER; i++) {
            int k = t + NT * i;
            int m = (k < S_LEN - k) ? k : (S_LEN - k);
            float nf = (float)(2 * m) * (1.0f / (float)S_LEN);
            float tt = nf * 5.0f;
            float lb = __expf(-0.5f * tt * tt);
            float hd = 0.5f / (1.0f + __expf(-(nf - 0.6f) * 10.0f));
            float bg = fmaxf(1.0f + lb - hd, 0.0f);

            float scaled = nf * 4095.0f;
            float fl  = floorf(scaled);
            int   lo  = (int)fl;
            int   hi  = (int)ceilf(scaled);
            float fr  = scaled - fl;

            const float4* p2lo = (const float4*)(P2w + (size_t)lo * RANK);
            const float4* p2hi = (const float4*)(P2w + (size_t)hi * RANK);
            float4 a0 = p2lo[0], a1 = p2lo[1];
            float4 b0 = p2hi[0], b1 = p2hi[1];
            float dlo = P2b[lo]
                      + hh[0]*a0.x + hh[1]*a0.y + hh[2]*a0.z + hh[3]*a0.w
                      + hh[4]*a1.x + hh[5]*a1.y + hh[6]*a1.z + hh[7]*a1.w;
            float dhi = P2b[hi]
                      + hh[0]*b0.x + hh[1]*b0.y + hh[2]*b0.z + hh[3]*b0.w
                      + hh[4]*b1.x + hh[5]*b1.y + hh[6]*b1.z + hh[7]*b1.w;
            float di = dlo + (dhi - dlo) * fr;
            float g  = fmaxf(bg + alpha * di, 0.0f);

            sre[k] *= g;
            sim[k] *= g;
        }
    }
    __builtin_amdgcn_sched_barrier(0);

    // phase 2b-p: accumulate p rank-8 partials only (16 accum live, ~30 peak)
    {
        float pr[RANK], pim[RANK];
#pragma unroll
        for (int r = 0; r < RANK; r++) { pr[r]=0.f; pim[r]=0.f; }

        for (int i = 0; i < PER; i++) {
            int k = t + NT * i;
            float zr = sre[k];
            float zi = sim[k];
#pragma unroll
            for (int r = 0; r < RANK; r++) {
                float u_ = Ur[r * S_LEN + k], v_ = Ui[r * S_LEN + k];
                pr[r]  += zr * u_ - zi * v_;
                pim[r] += zr * v_ + zi * u_;
            }
        }

#pragma unroll
        for (int r = 0; r < RANK; r++) {
#pragma unroll
            for (int off = 32; off > 0; off >>= 1) {
                pr[r]  += __shfl_xor(pr[r],  off, 64);
                pim[r] += __shfl_xor(pim[r], off, 64);
            }
        }
        if (lane == 0) {
#pragma unroll
            for (int r = 0; r < RANK; r++) {
                red[wid * 32 + r]      = pr[r];
                red[wid * 32 + 8 + r]  = pim[r];
            }
        }
    }
    __builtin_amdgcn_sched_barrier(0);

    // phase 2b-q: accumulate q rank-8 partials only (16 accum live)
    {
        float qr[RANK], qim[RANK];
#pragma unroll
        for (int r = 0; r < RANK; r++) { qr[r]=0.f; qim[r]=0.f; }

        for (int i = 0; i < PER; i++) {
            int k = t + NT * i;
            float zr = sre[k];
            float zi = sim[k];
#pragma unroll
            for (int r = 0; r < RANK; r++) {
                float w_ = Vr[r * S_LEN + k], y_ = Vi[r * S_LEN + k];
                qr[r]  += zr * w_ - zi * y_;
                qim[r] += zr * y_ + zi * w_;
            }
        }

#pragma unroll
        for (int r = 0; r < RANK; r++) {
#pragma unroll
            for (int off = 32; off > 0; off >>= 1) {
                qr[r]  += __shfl_xor(qr[r],  off, 64);
                qim[r] += __shfl_xor(qim[r], off, 64);
            }
        }
        if (lane == 0) {
#pragma unroll
            for (int r = 0; r < RANK; r++) {
                red[wid * 32 + 16 + r] = qr[r];
                red[wid * 32 + 24 + r] = qim[r];
            }
        }
        __syncthreads();
        if (t < 32) {
            float v = 0.0f;
#pragma unroll
            for (int w = 0; w < 8; w++) v += red[w * 32 + t];
            red[t] = v;
        }
        __syncthreads();
        if (t < RANK) {
            float prr = red[t],      pii = red[8 + t];
            float qrr = red[16 + t], qii = red[24 + t];
            gam[t]        = prr * qrr + pii * qii;  // Re(p * conj(q))
            gam[RANK + t] = pii * qrr - prr * qii;  // Im(p * conj(q))
        }
        __syncthreads();
    }

    // phase 4: z[k] += sum_r gamma[r] * (Wr[k,r] + i*Wi[k,r])
    {
        float gr[RANK], gi[RANK];
#pragma unroll
        for (int r = 0; r < RANK; r++) { gr[r] = gam[r]; gi[r] = gam[RANK + r]; }
        const float4* Wr4 = (const float4*)Wr;
        const float4* Wi4 = (const float4*)Wi;
        for (int i = 0; i < PER; i++) {
            int k = t + NT * i;
            float4 wa = Wr4[k * 2], wb = Wr4[k * 2 + 1];
            float4 va = Wi4[k * 2], vb = Wi4[k * 2 + 1];
            float wr_[RANK] = { wa.x, wa.y, wa.z, wa.w, wb.x, wb.y, wb.z, wb.w };
            float wi_[RANK] = { va.x, va.y, va.z, va.w, vb.x, vb.y, vb.z, vb.w };
            float ar = 0.f, ai = 0.f;
#pragma unroll
            for (int r = 0; r < RANK; r++) {
                ar += gr[r] * wr_[r] - gi[r] * wi_[r];
                ai += gr[r] * wi_[r] + gi[r] * wr_[r];
            }
            sre[k] += ar;
            sim[k] += ai;
        }
        __syncthreads();
    }

    // ================= inverse FFT: natural k in -> natural n out ==============
    {
        // round 1: read z linear, DFT over k4
#pragma unroll
        for (int c=0;c<8;c++){ ur[c] = sre[t + 512*c]; ui[c] = sim[t + 512*c]; }
        dft8<1>(ur, ui);
        __syncthreads();   // z consumed before A overwrites
        const int baseA = (t & 63) + 512 * (t >> 6);
#pragma unroll
        for (int e=0;e<8;e++){ sre[baseA + 64*e] = ur[e]; sim[baseA + 64*e] = ui[e]; }
    }
    __syncthreads();
    {
#pragma unroll
        for (int m=0;m<8;m++){ ur[m] = sre[t + 512*m]; ui[m] = sim[t + 512*m]; }
        twiddle8<1>(ur, ui, TWO_PI * (float)(t >> 6) * (1.0f/64.0f));
        dft8<1>(ur, ui);
        __syncthreads();
        const int baseB = (t & 7) + 8*(t >> 6) + 520*((t >> 3) & 7);
#pragma unroll
        for (int e=0;e<8;e++){ sre[baseB + 64*e] = ur[e]; sim[baseB + 64*e] = ui[e]; }
    }
    __syncthreads();
    {
#pragma unroll
        for (int m=0;m<8;m++){ ur[m] = sre[t + 520*m]; ui[m] = sim[t + 520*m]; }
        twiddle8<1>(ur, ui, TWO_PI * (float)(t >> 3) * (1.0f/512.0f));
        dft8<1>(ur, ui);
        __syncthreads();
        const int baseC = (t >> 3) + 520*(t & 7);
#pragma unroll
        for (int e=0;e<8;e++){ sre[baseC + 64*e] = ur[e]; sim[baseC + 64*e] = ui[e]; }
    }
    __syncthreads();
    {
#pragma unroll
        for (int m=0;m<8;m++){ ur[m] = sre[t + 520*m]; ui[m] = sim[t + 520*m]; }
        twiddle8<1>(ur, ui, TWO_PI * (float)t * (1.0f/4096.0f));
        dft8<1>(ur, ui);
        // write real part straight to global: out[n], n = t + 512*e (coalesced)
        float* orow = out + (size_t)row * S_LEN;
        const float scale = 1.0f / (float)S_LEN;
#pragma unroll
        for (int e=0;e<8;e++){
            orow[t + 512*e] = ur[e] * scale;
        }
    }
}

extern "C" void kernel_launch(void* const* d_in, const int* in_sizes, int n_in,
                              void* d_out, int out_size, void* d_ws, size_t ws_size,
                              hipStream_t stream) {
    const float* x    = (const float*)d_in[0];
    const float* Ur   = (const float*)d_in[1];
    const float* Ui   = (const float*)d_in[2];
    const float* Vr   = (const float*)d_in[3];
    const float* Vi   = (const float*)d_in[4];
    const float* Wr   = (const float*)d_in[5];
    const float* Wi   = (const float*)d_in[6];
    const float* P1w  = (const float*)d_in[7];
    const float* P1b  = (const float*)d_in[8];
    const float* P2w  = (const float*)d_in[9];
    const float* P2b  = (const float*)d_in[10];
    const float* alph = (const float*)d_in[11];

    recip_mixer<<<dim3(2048), dim3(NT), 0, stream>>>(
        x, Ur, Ui, Vr, Vi, Wr, Wi, P1w, P1b, P2w, P2b, alph, (float*)d_out);
}

// Round 6
// 263.451 us; speedup vs baseline: 1.2999x; 1.2999x over previous
//
#include <hip/hip_runtime.h>

#define S_LEN 4096
#define NT 512
#define PER 8
#define RANK 8
#define BP 4160   // per-buffer float2 count (max transpose addr 4151)
#define TWO_PI 6.2831853071795864769f

__device__ __forceinline__ void cmul(float& xr, float& xi, float cr, float ci){
    float tr = xr*cr - xi*ci;
    xi = xr*ci + xi*cr;
    xr = tr;
}

// 4-point DFT, in place. SIGN=-1 forward (W=e^{-i}), SIGN=+1 inverse.
template<int SIGN>
__device__ __forceinline__ void dft4(float& ar,float& ai,float& br,float& bi,
                                     float& cr,float& ci,float& dr,float& di){
    float Ar=ar+cr, Ai=ai+ci;
    float Br=ar-cr, Bi=ai-ci;
    float Cr=br+dr, Ci=bi+di;
    float Dr, Di;
    if (SIGN < 0){ Dr = bi-di; Di = dr-br; }   // -i*(b-d)
    else         { Dr = di-bi; Di = br-dr; }   // +i*(b-d)
    ar=Ar+Cr; ai=Ai+Ci;
    br=Br+Dr; bi=Bi+Di;
    cr=Ar-Cr; ci=Ai-Ci;
    dr=Br-Dr; di=Bi-Di;
}

// 8-point DFT in registers, natural-order in AND out (even/odd radix-2 split).
template<int SIGN>
__device__ __forceinline__ void dft8(float ur[8], float ui[8]){
    const float h = 0.70710678118654752f;
    float er0=ur[0], ei0=ui[0], er1=ur[2], ei1=ui[2];
    float er2=ur[4], ei2=ui[4], er3=ur[6], ei3=ui[6];
    float fr0=ur[1], fi0=ui[1], fr1=ur[3], fi1=ui[3];
    float fr2=ur[5], fi2=ui[5], fr3=ur[7], fi3=ui[7];
    dft4<SIGN>(er0,ei0, er1,ei1, er2,ei2, er3,ei3);   // E = DFT4(x0,x2,x4,x6)
    dft4<SIGN>(fr0,fi0, fr1,fi1, fr2,fi2, fr3,fi3);   // O = DFT4(x1,x3,x5,x7)
    // O[k] *= W8^k
    {   const float c =  h, s_ = (SIGN<0) ? -h : h;
        cmul(fr1, fi1, c, s_); }
    {   float tr = fr2, ti = fi2;
        if (SIGN < 0){ fr2 =  ti; fi2 = -tr; }   // *(-i)
        else         { fr2 = -ti; fi2 =  tr; }   // *(+i)
    }
    {   const float c = -h, s_ = (SIGN<0) ? -h : h;
        cmul(fr3, fi3, c, s_); }
    ur[0]=er0+fr0; ui[0]=ei0+fi0;
    ur[1]=er1+fr1; ui[1]=ei1+fi1;
    ur[2]=er2+fr2; ui[2]=ei2+fi2;
    ur[3]=er3+fr3; ui[3]=ei3+fi3;
    ur[4]=er0-fr0; ui[4]=ei0-fi0;
    ur[5]=er1-fr1; ui[5]=ei1-fi1;
    ur[6]=er2-fr2; ui[6]=ei2-fi2;
    ur[7]=er3-fr3; ui[7]=ei3-fi3;
}

// multiply u[m] by exp(SIGN * i * theta * m), m = 0..7 (iterative powers)
template<int SIGN>
__device__ __forceinline__ void twiddle8(float ur[8], float ui[8], float theta){
    float s, c;
    __sincosf(theta, &s, &c);
    const float wi = (SIGN < 0) ? -s : s;
    const float wr = c;
    float pr = wr, pi = wi;      // w^1
    cmul(ur[1], ui[1], pr, pi);
#pragma unroll
    for (int m=2;m<8;m++){
        float nr = pr*wr - pi*wi;
        pi = pr*wi + pi*wr;
        pr = nr;
        cmul(ur[m], ui[m], pr, pi);
    }
}

// 4096 = 8*8*8*8, n = n1 + 8n2 + 64n3 + 512n4, k = e1 + 8e2 + 64e3 + 512e4.
// Round r DFTs over n_{5-r}; twiddles W_{8^r}^{digit * k_so_far}.
// LDS: PING-PONG float2 buffers sz[0]/sz[1] (re,im packed -> ds_*_b64, half
// the LDS ops and half the address math of split arrays). Layouts per round
// keep every READ linear (t + {512,520}*m):
//   A[n1+8n2 + 64e1 + 512n3]       in buf0 (fwd) — write conflict-free
//   B[n1 + 8e1 + 64e2 + 520n2]     in buf1 — write ~4-way b64 (acceptable)
//   C[(e1+8e2) + 64e3 + 520n1]     in buf0 — write ~4-way b64
//   z linear [t + 512e4]           in buf1
// Ping-pong removes all mid-round "consumed before overwrite" barriers:
// 18 syncs -> 12. LDS 2*4160*8 ~ 66.6KB -> 2 blocks/CU * 8 waves = 16 waves
// = exactly the VGPR=64 residency ceiling (measured r2-r5: effective pool
// ~256 regs/SIMD; 64->4 waves, 48-cap SPILLS 480MB — true peak in (48,64]).
// So: accept VGPR=64, minimize LDS latency events + barriers instead.

__global__ __launch_bounds__(NT, 4) void recip_mixer(
    const float* __restrict__ x,
    const float* __restrict__ Ur, const float* __restrict__ Ui,
    const float* __restrict__ Vr, const float* __restrict__ Vi,
    const float* __restrict__ Wr, const float* __restrict__ Wi,
    const float* __restrict__ P1w, const float* __restrict__ P1b,
    const float* __restrict__ P2w, const float* __restrict__ P2b,
    const float* __restrict__ alphap,
    float* __restrict__ out)
{
    __shared__ float2 sz[2][BP];
    __shared__ float red[256];
    __shared__ float hid[RANK];
    __shared__ float gam[2 * RANK];

    const int t    = threadIdx.x;
    const int row  = blockIdx.x;
    const int lane = t & 63;
    const int wid  = t >> 6;

    float ur[8], ui[8];

    const int baseA = (t & 63) + 512 * (t >> 6);
    const int baseB = (t & 7) + 8*(t >> 6) + 520*((t >> 3) & 7);
    const int baseC = (t >> 3) + 520*(t & 7);

    // ================= forward FFT: natural in -> natural k out =================
    {
        // R1: t = n1+8n2+64n3; DFT over n4 (global reads coalesced) -> buf0 (A)
        const float* xrow = x + (size_t)row * S_LEN;
#pragma unroll
        for (int c=0;c<8;c++){ ur[c] = xrow[t + 512*c]; ui[c] = 0.0f; }
        dft8<-1>(ur, ui);
#pragma unroll
        for (int e=0;e<8;e++) sz[0][baseA + 64*e] = make_float2(ur[e], ui[e]);
    }
    __syncthreads();
    {
        // R2: read A linear, twiddle W_64^{n3 e1}, DFT over n3 -> buf1 (B)
#pragma unroll
        for (int m=0;m<8;m++){ float2 v = sz[0][t + 512*m]; ur[m]=v.x; ui[m]=v.y; }
        twiddle8<-1>(ur, ui, TWO_PI * (float)(t >> 6) * (1.0f/64.0f));
        dft8<-1>(ur, ui);
#pragma unroll
        for (int e=0;e<8;e++) sz[1][baseB + 64*e] = make_float2(ur[e], ui[e]);
    }
    __syncthreads();
    {
        // R3: read B linear, twiddle W_512^{n2 (e1+8e2)}, DFT over n2 -> buf0 (C)
#pragma unroll
        for (int m=0;m<8;m++){ float2 v = sz[1][t + 520*m]; ur[m]=v.x; ui[m]=v.y; }
        twiddle8<-1>(ur, ui, TWO_PI * (float)(t >> 3) * (1.0f/512.0f));
        dft8<-1>(ur, ui);
#pragma unroll
        for (int e=0;e<8;e++) sz[0][baseC + 64*e] = make_float2(ur[e], ui[e]);
    }
    __syncthreads();
    {
        // R4: read C linear, twiddle W_4096^{n1 t}, DFT over n1 -> buf1 (z linear)
#pragma unroll
        for (int m=0;m<8;m++){ float2 v = sz[0][t + 520*m]; ur[m]=v.x; ui[m]=v.y; }
        twiddle8<-1>(ur, ui, TWO_PI * (float)t * (1.0f/4096.0f));
        dft8<-1>(ur, ui);
#pragma unroll
        for (int e=0;e<8;e++) sz[1][t + 512*e] = make_float2(ur[e], ui[e]);
    }
    __syncthreads();

    // ================= middle phase (z in buf1, linear) =====
    // phase 1: hidden = relu(P1w @ [Re z ; Im z] + P1b)
    {
        float h[RANK];
#pragma unroll
        for (int r = 0; r < RANK; r++) h[r] = 0.0f;
        for (int i = 0; i < PER; i++) {
            int k = t + NT * i;
            float2 v = sz[1][k];
#pragma unroll
            for (int r = 0; r < RANK; r++) {
                h[r] += v.x * P1w[r * (2 * S_LEN) + k]
                      + v.y * P1w[r * (2 * S_LEN) + S_LEN + k];
            }
        }
#pragma unroll
        for (int r = 0; r < RANK; r++) {
#pragma unroll
            for (int off = 32; off > 0; off >>= 1)
                h[r] += __shfl_xor(h[r], off, 64);
        }
        if (lane == 0) {
#pragma unroll
            for (int r = 0; r < RANK; r++) red[wid * RANK + r] = h[r];
        }
        __syncthreads();
        if (t < RANK) {
            float v = 0.0f;
#pragma unroll
            for (int w = 0; w < 8; w++) v += red[w * RANK + t];
            hid[t] = fmaxf(v + P1b[t], 0.0f);
        }
        __syncthreads();
    }

    // phase 2a: per-k gain, scale z in LDS (no accumulators live; own slots only)
    {
        float hh[RANK];
#pragma unroll
        for (int r = 0; r < RANK; r++) hh[r] = hid[r];
        const float alpha = alphap[0];

        for (int i = 0; i < PER; i++) {
            int k = t + NT * i;
            int m = (k < S_LEN - k) ? k : (S_LEN - k);
            float nf = (float)(2 * m) * (1.0f / (float)S_LEN);
            float tt = nf * 5.0f;
            float lb = __expf(-0.5f * tt * tt);
            float hd = 0.5f / (1.0f + __expf(-(nf - 0.6f) * 10.0f));
            float bg = fmaxf(1.0f + lb - hd, 0.0f);

            float scaled = nf * 4095.0f;
            float fl  = floorf(scaled);
            int   lo  = (int)fl;
            int   hi  = (int)ceilf(scaled);
            float fr  = scaled - fl;

            const float4* p2lo = (const float4*)(P2w + (size_t)lo * RANK);
            const float4* p2hi = (const float4*)(P2w + (size_t)hi * RANK);
            float4 a0 = p2lo[0], a1 = p2lo[1];
            float4 b0 = p2hi[0], b1 = p2hi[1];
            float dlo = P2b[lo]
                      + hh[0]*a0.x + hh[1]*a0.y + hh[2]*a0.z + hh[3]*a0.w
                      + hh[4]*a1.x + hh[5]*a1.y + hh[6]*a1.z + hh[7]*a1.w;
            float dhi = P2b[hi]
                      + hh[0]*b0.x + hh[1]*b0.y + hh[2]*b0.z + hh[3]*b0.w
                      + hh[4]*b1.x + hh[5]*b1.y + hh[6]*b1.z + hh[7]*b1.w;
            float di = dlo + (dhi - dlo) * fr;
            float g  = fmaxf(bg + alpha * di, 0.0f);

            float2 v = sz[1][k];
            v.x *= g; v.y *= g;
            sz[1][k] = v;
        }
    }
    // keep pass-B loads from being hoisted into pass A (would re-inflate VGPR peak)
    __builtin_amdgcn_sched_barrier(0);

    // phase 2b: accumulate p/q rank-8 partials from scaled z (fits VGPR=64, r4-proven)
    {
        float pr[RANK], pim[RANK], qr[RANK], qim[RANK];
#pragma unroll
        for (int r = 0; r < RANK; r++) { pr[r]=0.f; pim[r]=0.f; qr[r]=0.f; qim[r]=0.f; }

        for (int i = 0; i < PER; i++) {
            int k = t + NT * i;
            float2 v = sz[1][k];
            float zr = v.x, zi = v.y;
#pragma unroll
            for (int r = 0; r < RANK; r++) {
                float u_ = Ur[r * S_LEN + k], v_ = Ui[r * S_LEN + k];
                pr[r]  += zr * u_ - zi * v_;
                pim[r] += zr * v_ + zi * u_;
                float w_ = Vr[r * S_LEN + k], y_ = Vi[r * S_LEN + k];
                qr[r]  += zr * w_ - zi * y_;
                qim[r] += zr * y_ + zi * w_;
            }
        }

#pragma unroll
        for (int r = 0; r < RANK; r++) {
#pragma unroll
            for (int off = 32; off > 0; off >>= 1) {
                pr[r]  += __shfl_xor(pr[r],  off, 64);
                pim[r] += __shfl_xor(pim[r], off, 64);
                qr[r]  += __shfl_xor(qr[r],  off, 64);
                qim[r] += __shfl_xor(qim[r], off, 64);
            }
        }
        if (lane == 0) {
#pragma unroll
            for (int r = 0; r < RANK; r++) {
                red[wid * 32 + r]      = pr[r];
                red[wid * 32 + 8 + r]  = pim[r];
                red[wid * 32 + 16 + r] = qr[r];
                red[wid * 32 + 24 + r] = qim[r];
            }
        }
        __syncthreads();
        if (t < 32) {
            float v = 0.0f;
#pragma unroll
            for (int w = 0; w < 8; w++) v += red[w * 32 + t];
            red[t] = v;
        }
        __syncthreads();
        if (t < RANK) {
            float prr = red[t],      pii = red[8 + t];
            float qrr = red[16 + t], qii = red[24 + t];
            gam[t]        = prr * qrr + pii * qii;  // Re(p * conj(q))
            gam[RANK + t] = pii * qrr - prr * qii;  // Im(p * conj(q))
        }
        __syncthreads();
    }

    // phase 4: z[k] += sum_r gamma[r] * (Wr[k,r] + i*Wi[k,r])  (own slots only;
    // inverse R1 reads the SAME per-thread slots -> no barrier needed after)
    {
        float gr[RANK], gi[RANK];
#pragma unroll
        for (int r = 0; r < RANK; r++) { gr[r] = gam[r]; gi[r] = gam[RANK + r]; }
        const float4* Wr4 = (const float4*)Wr;
        const float4* Wi4 = (const float4*)Wi;
        for (int i = 0; i < PER; i++) {
            int k = t + NT * i;
            float4 wa = Wr4[k * 2], wb = Wr4[k * 2 + 1];
            float4 va = Wi4[k * 2], vb = Wi4[k * 2 + 1];
            float wr_[RANK] = { wa.x, wa.y, wa.z, wa.w, wb.x, wb.y, wb.z, wb.w };
            float wi_[RANK] = { va.x, va.y, va.z, va.w, vb.x, vb.y, vb.z, vb.w };
            float ar = 0.f, ai = 0.f;
#pragma unroll
            for (int r = 0; r < RANK; r++) {
                ar += gr[r] * wr_[r] - gi[r] * wi_[r];
                ai += gr[r] * wi_[r] + gi[r] * wr_[r];
            }
            float2 v = sz[1][k];
            v.x += ar; v.y += ai;
            sz[1][k] = v;
        }
    }
    // no __syncthreads: inverse R1 reads exactly the slots this thread wrote

    // ================= inverse FFT: natural k in -> natural n out ==============
    {
        // I1: read z linear (own slots), DFT over k4 -> buf0 (A)
#pragma unroll
        for (int c=0;c<8;c++){ float2 v = sz[1][t + 512*c]; ur[c]=v.x; ui[c]=v.y; }
        dft8<1>(ur, ui);
#pragma unroll
        for (int e=0;e<8;e++) sz[0][baseA + 64*e] = make_float2(ur[e], ui[e]);
    }
    __syncthreads();
    {
        // I2: buf0 (A) -> buf1 (B)
#pragma unroll
        for (int m=0;m<8;m++){ float2 v = sz[0][t + 512*m]; ur[m]=v.x; ui[m]=v.y; }
        twiddle8<1>(ur, ui, TWO_PI * (float)(t >> 6) * (1.0f/64.0f));
        dft8<1>(ur, ui);
#pragma unroll
        for (int e=0;e<8;e++) sz[1][baseB + 64*e] = make_float2(ur[e], ui[e]);
    }
    __syncthreads();
    {
        // I3: buf1 (B) -> buf0 (C)
#pragma unroll
        for (int m=0;m<8;m++){ float2 v = sz[1][t + 520*m]; ur[m]=v.x; ui[m]=v.y; }
        twiddle8<1>(ur, ui, TWO_PI * (float)(t >> 3) * (1.0f/512.0f));
        dft8<1>(ur, ui);
#pragma unroll
        for (int e=0;e<8;e++) sz[0][baseC + 64*e] = make_float2(ur[e], ui[e]);
    }
    __syncthreads();
    {
        // I4: buf0 (C) -> global out (real part), n = t + 512*e (coalesced)
#pragma unroll
        for (int m=0;m<8;m++){ float2 v = sz[0][t + 520*m]; ur[m]=v.x; ui[m]=v.y; }
        twiddle8<1>(ur, ui, TWO_PI * (float)t * (1.0f/4096.0f));
        dft8<1>(ur, ui);
        float* orow = out + (size_t)row * S_LEN;
        const float scale = 1.0f / (float)S_LEN;
#pragma unroll
        for (int e=0;e<8;e++){
            orow[t + 512*e] = ur[e] * scale;
        }
    }
}

extern "C" void kernel_launch(void* const* d_in, const int* in_sizes, int n_in,
                              void* d_out, int out_size, void* d_ws, size_t ws_size,
                              hipStream_t stream) {
    const float* x    = (const float*)d_in[0];
    const float* Ur   = (const float*)d_in[1];
    const float* Ui   = (const float*)d_in[2];
    const float* Vr   = (const float*)d_in[3];
    const float* Vi   = (const float*)d_in[4];
    const float* Wr   = (const float*)d_in[5];
    const float* Wi   = (const float*)d_in[6];
    const float* P1w  = (const float*)d_in[7];
    const float* P1b  = (const float*)d_in[8];
    const float* P2w  = (const float*)d_in[9];
    const float* P2b  = (const float*)d_in[10];
    const float* alph = (const float*)d_in[11];

    recip_mixer<<<dim3(2048), dim3(NT), 0, stream>>>(
        x, Ur, Ui, Vr, Vi, Wr, Wi, P1w, P1b, P2w, P2b, alph, (float*)d_out);
}

// Round 7
// 245.816 us; speedup vs baseline: 1.3931x; 1.0717x over previous
//
#include <hip/hip_runtime.h>

#define S_LEN 4096
#define NT 512
#define PER 8
#define RANK 8
#define BP 4160   // per-buffer float count (max transpose addr 4151)
#define TWO_PI 6.2831853071795864769f

__device__ __forceinline__ void cmul(float& xr, float& xi, float cr, float ci){
    float tr = xr*cr - xi*ci;
    xi = xr*ci + xi*cr;
    xr = tr;
}

// 4-point DFT, in place. SIGN=-1 forward (W=e^{-i}), SIGN=+1 inverse.
template<int SIGN>
__device__ __forceinline__ void dft4(float& ar,float& ai,float& br,float& bi,
                                     float& cr,float& ci,float& dr,float& di){
    float Ar=ar+cr, Ai=ai+ci;
    float Br=ar-cr, Bi=ai-ci;
    float Cr=br+dr, Ci=bi+di;
    float Dr, Di;
    if (SIGN < 0){ Dr = bi-di; Di = dr-br; }   // -i*(b-d)
    else         { Dr = di-bi; Di = br-dr; }   // +i*(b-d)
    ar=Ar+Cr; ai=Ai+Ci;
    br=Br+Dr; bi=Bi+Di;
    cr=Ar-Cr; ci=Ai-Ci;
    dr=Br-Dr; di=Bi-Di;
}

// 8-point DFT in registers, natural-order in AND out (even/odd radix-2 split).
template<int SIGN>
__device__ __forceinline__ void dft8(float ur[8], float ui[8]){
    const float h = 0.70710678118654752f;
    float er0=ur[0], ei0=ui[0], er1=ur[2], ei1=ui[2];
    float er2=ur[4], ei2=ui[4], er3=ur[6], ei3=ui[6];
    float fr0=ur[1], fi0=ui[1], fr1=ur[3], fi1=ui[3];
    float fr2=ur[5], fi2=ui[5], fr3=ur[7], fi3=ui[7];
    dft4<SIGN>(er0,ei0, er1,ei1, er2,ei2, er3,ei3);   // E = DFT4(x0,x2,x4,x6)
    dft4<SIGN>(fr0,fi0, fr1,fi1, fr2,fi2, fr3,fi3);   // O = DFT4(x1,x3,x5,x7)
    // O[k] *= W8^k
    {   const float c =  h, s_ = (SIGN<0) ? -h : h;
        cmul(fr1, fi1, c, s_); }
    {   float tr = fr2, ti = fi2;
        if (SIGN < 0){ fr2 =  ti; fi2 = -tr; }   // *(-i)
        else         { fr2 = -ti; fi2 =  tr; }   // *(+i)
    }
    {   const float c = -h, s_ = (SIGN<0) ? -h : h;
        cmul(fr3, fi3, c, s_); }
    ur[0]=er0+fr0; ui[0]=ei0+fi0;
    ur[1]=er1+fr1; ui[1]=ei1+fi1;
    ur[2]=er2+fr2; ui[2]=ei2+fi2;
    ur[3]=er3+fr3; ui[3]=ei3+fi3;
    ur[4]=er0-fr0; ui[4]=ei0-fi0;
    ur[5]=er1-fr1; ui[5]=ei1-fi1;
    ur[6]=er2-fr2; ui[6]=ei2-fi2;
    ur[7]=er3-fr3; ui[7]=ei3-fi3;
}

// multiply u[m] by exp(SIGN * i * theta * m), m = 0..7 (iterative powers)
template<int SIGN>
__device__ __forceinline__ void twiddle8(float ur[8], float ui[8], float theta){
    float s, c;
    __sincosf(theta, &s, &c);
    const float wi = (SIGN < 0) ? -s : s;
    const float wr = c;
    float pr = wr, pi = wi;      // w^1
    cmul(ur[1], ui[1], pr, pi);
#pragma unroll
    for (int m=2;m<8;m++){
        float nr = pr*wr - pi*wi;
        pi = pr*wi + pi*wr;
        pr = nr;
        cmul(ur[m], ui[m], pr, pi);
    }
}

// 4096 = 8*8*8*8, n = n1 + 8n2 + 64n3 + 512n4, k = e1 + 8e2 + 64e3 + 512e4.
// Round r DFTs over n_{5-r}; twiddles W_{8^r}^{digit * k_so_far}.
// LDS: ping-pong buffer PAIRS of SPLIT float arrays (s0r/s0i, s1r/s1i).
//   r6 lesson: float2/b64 packing tripled bank conflicts (4-way) AND re-spilled
//   (~85MB scratch traffic); split b32 arrays are 2-way (free) and spill-free
//   (r4-proven). Ping-pong removes every "consumed-before-overwrite" barrier
//   plus the R4->phase1 and phase4->I1 own-slot handoffs: 18 -> 11 syncs.
// Layouts (every READ linear t + {512,520}*m):
//   A[n1+8n2 + 64e1 + 512n3]   buf0   B[n1 + 8e1 + 64e2 + 520n2]   buf1
//   C[(e1+8e2) + 64e3 + 520n1] buf0   z linear [t + 512e4]         buf1
// LDS 4*4160*4 ~ 66.5KB -> 2 blocks/CU; residency is VGPR-limited anyway
// (measured r2-r6: pool ~256 regs/SIMD; VGPR=64 -> 4 waves/SIMD = 43% occ;
// cap 48 spills 480MB: true peak in (48,64]; accept 64).

__global__ __launch_bounds__(NT, 4) void recip_mixer(
    const float* __restrict__ x,
    const float* __restrict__ Ur, const float* __restrict__ Ui,
    const float* __restrict__ Vr, const float* __restrict__ Vi,
    const float* __restrict__ Wr, const float* __restrict__ Wi,
    const float* __restrict__ P1w, const float* __restrict__ P1b,
    const float* __restrict__ P2w, const float* __restrict__ P2b,
    const float* __restrict__ alphap,
    float* __restrict__ out)
{
    __shared__ float s0r[BP], s0i[BP];
    __shared__ float s1r[BP], s1i[BP];
    __shared__ float red[256];
    __shared__ float hid[RANK];
    __shared__ float gam[2 * RANK];

    const int t    = threadIdx.x;
    const int row  = blockIdx.x;
    const int lane = t & 63;
    const int wid  = t >> 6;

    float ur[8], ui[8];

    const int baseA = (t & 63) + 512 * (t >> 6);
    const int baseB = (t & 7) + 8*(t >> 6) + 520*((t >> 3) & 7);
    const int baseC = (t >> 3) + 520*(t & 7);

    // ================= forward FFT: natural in -> natural k out =================
    {
        // R1: t = n1+8n2+64n3; DFT over n4 (global reads coalesced) -> buf0 (A)
        const float* xrow = x + (size_t)row * S_LEN;
#pragma unroll
        for (int c=0;c<8;c++){ ur[c] = xrow[t + 512*c]; ui[c] = 0.0f; }
        dft8<-1>(ur, ui);
#pragma unroll
        for (int e=0;e<8;e++){ s0r[baseA + 64*e] = ur[e]; s0i[baseA + 64*e] = ui[e]; }
    }
    __syncthreads();
    {
        // R2: read A linear, twiddle W_64^{n3 e1}, DFT over n3 -> buf1 (B)
#pragma unroll
        for (int m=0;m<8;m++){ ur[m] = s0r[t + 512*m]; ui[m] = s0i[t + 512*m]; }
        twiddle8<-1>(ur, ui, TWO_PI * (float)(t >> 6) * (1.0f/64.0f));
        dft8<-1>(ur, ui);
#pragma unroll
        for (int e=0;e<8;e++){ s1r[baseB + 64*e] = ur[e]; s1i[baseB + 64*e] = ui[e]; }
    }
    __syncthreads();
    {
        // R3: read B linear, twiddle W_512^{n2 (e1+8e2)}, DFT over n2 -> buf0 (C)
#pragma unroll
        for (int m=0;m<8;m++){ ur[m] = s1r[t + 520*m]; ui[m] = s1i[t + 520*m]; }
        twiddle8<-1>(ur, ui, TWO_PI * (float)(t >> 3) * (1.0f/512.0f));
        dft8<-1>(ur, ui);
#pragma unroll
        for (int e=0;e<8;e++){ s0r[baseC + 64*e] = ur[e]; s0i[baseC + 64*e] = ui[e]; }
    }
    __syncthreads();
    {
        // R4: read C linear, twiddle W_4096^{n1 t}, DFT over n1 -> buf1 (z linear)
#pragma unroll
        for (int m=0;m<8;m++){ ur[m] = s0r[t + 520*m]; ui[m] = s0i[t + 520*m]; }
        twiddle8<-1>(ur, ui, TWO_PI * (float)t * (1.0f/4096.0f));
        dft8<-1>(ur, ui);
#pragma unroll
        for (int e=0;e<8;e++){ s1r[t + 512*e] = ur[e]; s1i[t + 512*e] = ui[e]; }
    }
    // no barrier: phase 1 reads exactly the z slots this thread just wrote

    // ================= middle phase (z in buf1, linear) =====
    // phase 1: hidden = relu(P1w @ [Re z ; Im z] + P1b)
    {
        float h[RANK];
#pragma unroll
        for (int r = 0; r < RANK; r++) h[r] = 0.0f;
        for (int i = 0; i < PER; i++) {
            int k = t + NT * i;
            float zr = s1r[k], zi = s1i[k];
#pragma unroll
            for (int r = 0; r < RANK; r++) {
                h[r] += zr * P1w[r * (2 * S_LEN) + k]
                      + zi * P1w[r * (2 * S_LEN) + S_LEN + k];
            }
        }
#pragma unroll
        for (int r = 0; r < RANK; r++) {
#pragma unroll
            for (int off = 32; off > 0; off >>= 1)
                h[r] += __shfl_xor(h[r], off, 64);
        }
        if (lane == 0) {
#pragma unroll
            for (int r = 0; r < RANK; r++) red[wid * RANK + r] = h[r];
        }
        __syncthreads();
        if (t < RANK) {
            float v = 0.0f;
#pragma unroll
            for (int w = 0; w < 8; w++) v += red[w * RANK + t];
            hid[t] = fmaxf(v + P1b[t], 0.0f);
        }
        __syncthreads();
    }

    // phase 2a: per-k gain, scale z in LDS (no accumulators live; own slots only)
    {
        float hh[RANK];
#pragma unroll
        for (int r = 0; r < RANK; r++) hh[r] = hid[r];
        const float alpha = alphap[0];

        for (int i = 0; i < PER; i++) {
            int k = t + NT * i;
            int m = (k < S_LEN - k) ? k : (S_LEN - k);
            float nf = (float)(2 * m) * (1.0f / (float)S_LEN);
            float tt = nf * 5.0f;
            float lb = __expf(-0.5f * tt * tt);
            float hd = 0.5f / (1.0f + __expf(-(nf - 0.6f) * 10.0f));
            float bg = fmaxf(1.0f + lb - hd, 0.0f);

            float scaled = nf * 4095.0f;
            float fl  = floorf(scaled);
            int   lo  = (int)fl;
            int   hi  = (int)ceilf(scaled);
            float fr  = scaled - fl;

            const float4* p2lo = (const float4*)(P2w + (size_t)lo * RANK);
            const float4* p2hi = (const float4*)(P2w + (size_t)hi * RANK);
            float4 a0 = p2lo[0], a1 = p2lo[1];
            float4 b0 = p2hi[0], b1 = p2hi[1];
            float dlo = P2b[lo]
                      + hh[0]*a0.x + hh[1]*a0.y + hh[2]*a0.z + hh[3]*a0.w
                      + hh[4]*a1.x + hh[5]*a1.y + hh[6]*a1.z + hh[7]*a1.w;
            float dhi = P2b[hi]
                      + hh[0]*b0.x + hh[1]*b0.y + hh[2]*b0.z + hh[3]*b0.w
                      + hh[4]*b1.x + hh[5]*b1.y + hh[6]*b1.z + hh[7]*b1.w;
            float di = dlo + (dhi - dlo) * fr;
            float g  = fmaxf(bg + alpha * di, 0.0f);

            s1r[k] *= g;
            s1i[k] *= g;
        }
    }
    // keep pass-B loads from being hoisted into pass A (would re-inflate VGPR peak)
    __builtin_amdgcn_sched_barrier(0);

    // phase 2b: accumulate p/q rank-8 partials from scaled z (fits VGPR=64, r4-proven)
    {
        float pr[RANK], pim[RANK], qr[RANK], qim[RANK];
#pragma unroll
        for (int r = 0; r < RANK; r++) { pr[r]=0.f; pim[r]=0.f; qr[r]=0.f; qim[r]=0.f; }

        for (int i = 0; i < PER; i++) {
            int k = t + NT * i;
            float zr = s1r[k];
            float zi = s1i[k];
#pragma unroll
            for (int r = 0; r < RANK; r++) {
                float u_ = Ur[r * S_LEN + k], v_ = Ui[r * S_LEN + k];
                pr[r]  += zr * u_ - zi * v_;
                pim[r] += zr * v_ + zi * u_;
                float w_ = Vr[r * S_LEN + k], y_ = Vi[r * S_LEN + k];
                qr[r]  += zr * w_ - zi * y_;
                qim[r] += zr * y_ + zi * w_;
            }
        }

#pragma unroll
        for (int r = 0; r < RANK; r++) {
#pragma unroll
            for (int off = 32; off > 0; off >>= 1) {
                pr[r]  += __shfl_xor(pr[r],  off, 64);
                pim[r] += __shfl_xor(pim[r], off, 64);
                qr[r]  += __shfl_xor(qr[r],  off, 64);
                qim[r] += __shfl_xor(qim[r], off, 64);
            }
        }
        if (lane == 0) {
#pragma unroll
            for (int r = 0; r < RANK; r++) {
                red[wid * 32 + r]      = pr[r];
                red[wid * 32 + 8 + r]  = pim[r];
                red[wid * 32 + 16 + r] = qr[r];
                red[wid * 32 + 24 + r] = qim[r];
            }
        }
        __syncthreads();
        if (t < 32) {
            float v = 0.0f;
#pragma unroll
            for (int w = 0; w < 8; w++) v += red[w * 32 + t];
            red[t] = v;
        }
        __syncthreads();
        if (t < RANK) {
            float prr = red[t],      pii = red[8 + t];
            float qrr = red[16 + t], qii = red[24 + t];
            gam[t]        = prr * qrr + pii * qii;  // Re(p * conj(q))
            gam[RANK + t] = pii * qrr - prr * qii;  // Im(p * conj(q))
        }
        __syncthreads();
    }

    // phase 4: z[k] += sum_r gamma[r] * (Wr[k,r] + i*Wi[k,r])  (own slots only;
    // inverse I1 reads the SAME per-thread slots -> no barrier needed after)
    {
        float gr[RANK], gi[RANK];
#pragma unroll
        for (int r = 0; r < RANK; r++) { gr[r] = gam[r]; gi[r] = gam[RANK + r]; }
        const float4* Wr4 = (const float4*)Wr;
        const float4* Wi4 = (const float4*)Wi;
        for (int i = 0; i < PER; i++) {
            int k = t + NT * i;
            float4 wa = Wr4[k * 2], wb = Wr4[k * 2 + 1];
            float4 va = Wi4[k * 2], vb = Wi4[k * 2 + 1];
            float wr_[RANK] = { wa.x, wa.y, wa.z, wa.w, wb.x, wb.y, wb.z, wb.w };
            float wi_[RANK] = { va.x, va.y, va.z, va.w, vb.x, vb.y, vb.z, vb.w };
            float ar = 0.f, ai = 0.f;
#pragma unroll
            for (int r = 0; r < RANK; r++) {
                ar += gr[r] * wr_[r] - gi[r] * wi_[r];
                ai += gr[r] * wi_[r] + gi[r] * wr_[r];
            }
            s1r[k] += ar;
            s1i[k] += ai;
        }
    }
    // no barrier: I1 reads exactly the slots this thread wrote

    // ================= inverse FFT: natural k in -> natural n out ==============
    {
        // I1: read z linear (own slots), DFT over k4 -> buf0 (A)
#pragma unroll
        for (int c=0;c<8;c++){ ur[c] = s1r[t + 512*c]; ui[c] = s1i[t + 512*c]; }
        dft8<1>(ur, ui);
#pragma unroll
        for (int e=0;e<8;e++){ s0r[baseA + 64*e] = ur[e]; s0i[baseA + 64*e] = ui[e]; }
    }
    __syncthreads();
    {
        // I2: buf0 (A) -> buf1 (B)
#pragma unroll
        for (int m=0;m<8;m++){ ur[m] = s0r[t + 512*m]; ui[m] = s0i[t + 512*m]; }
        twiddle8<1>(ur, ui, TWO_PI * (float)(t >> 6) * (1.0f/64.0f));
        dft8<1>(ur, ui);
#pragma unroll
        for (int e=0;e<8;e++){ s1r[baseB + 64*e] = ur[e]; s1i[baseB + 64*e] = ui[e]; }
    }
    __syncthreads();
    {
        // I3: buf1 (B) -> buf0 (C)
#pragma unroll
        for (int m=0;m<8;m++){ ur[m] = s1r[t + 520*m]; ui[m] = s1i[t + 520*m]; }
        twiddle8<1>(ur, ui, TWO_PI * (float)(t >> 3) * (1.0f/512.0f));
        dft8<1>(ur, ui);
#pragma unroll
        for (int e=0;e<8;e++){ s0r[baseC + 64*e] = ur[e]; s0i[baseC + 64*e] = ui[e]; }
    }
    __syncthreads();
    {
        // I4: buf0 (C) -> global out (real part), n = t + 512*e (coalesced)
#pragma unroll
        for (int m=0;m<8;m++){ ur[m] = s0r[t + 520*m]; ui[m] = s0i[t + 520*m]; }
        twiddle8<1>(ur, ui, TWO_PI * (float)t * (1.0f/4096.0f));
        dft8<1>(ur, ui);
        float* orow = out + (size_t)row * S_LEN;
        const float scale = 1.0f / (float)S_LEN;
#pragma unroll
        for (int e=0;e<8;e++){
            orow[t + 512*e] = ur[e] * scale;
        }
    }
}

extern "C" void kernel_launch(void* const* d_in, const int* in_sizes, int n_in,
                              void* d_out, int out_size, void* d_ws, size_t ws_size,
                              hipStream_t stream) {
    const float* x    = (const float*)d_in[0];
    const float* Ur   = (const float*)d_in[1];
    const float* Ui   = (const float*)d_in[2];
    const float* Vr   = (const float*)d_in[3];
    const float* Vi   = (const float*)d_in[4];
    const float* Wr   = (const float*)d_in[5];
    const float* Wi   = (const float*)d_in[6];
    const float* P1w  = (const float*)d_in[7];
    const float* P1b  = (const float*)d_in[8];
    const float* P2w  = (const float*)d_in[9];
    const float* P2b  = (const float*)d_in[10];
    const float* alph = (const float*)d_in[11];

    recip_mixer<<<dim3(2048), dim3(NT), 0, stream>>>(
        x, Ur, Ui, Vr, Vi, Wr, Wi, P1w, P1b, P2w, P2b, alph, (float*)d_out);
}

// Round 8
// 213.785 us; speedup vs baseline: 1.6019x; 1.1498x over previous
//
#include <hip/hip_runtime.h>

#define S_LEN 4096
#define NT 512
#define PER 8
#define RANK 8
#define BP 4160      // padded FFT buffer float count (max transpose addr 4151)
#define NHALF 2049   // half-spectrum gain table (k = 0..2048)
#define TWO_PI 6.2831853071795864769f

__device__ __forceinline__ void cmul(float& xr, float& xi, float cr, float ci){
    float tr = xr*cr - xi*ci;
    xi = xr*ci + xi*cr;
    xr = tr;
}

// 4-point DFT, in place. SIGN=-1 forward, SIGN=+1 inverse.
template<int SIGN>
__device__ __forceinline__ void dft4(float& ar,float& ai,float& br,float& bi,
                                     float& cr,float& ci,float& dr,float& di){
    float Ar=ar+cr, Ai=ai+ci;
    float Br=ar-cr, Bi=ai-ci;
    float Cr=br+dr, Ci=bi+di;
    float Dr, Di;
    if (SIGN < 0){ Dr = bi-di; Di = dr-br; }
    else         { Dr = di-bi; Di = br-dr; }
    ar=Ar+Cr; ai=Ai+Ci;
    br=Br+Dr; bi=Bi+Di;
    cr=Ar-Cr; ci=Ai-Ci;
    dr=Br-Dr; di=Bi-Di;
}

// 8-point DFT in registers, natural-order in and out.
template<int SIGN>
__device__ __forceinline__ void dft8(float ur[8], float ui[8]){
    const float h = 0.70710678118654752f;
    float er0=ur[0], ei0=ui[0], er1=ur[2], ei1=ui[2];
    float er2=ur[4], ei2=ui[4], er3=ur[6], ei3=ui[6];
    float fr0=ur[1], fi0=ui[1], fr1=ur[3], fi1=ui[3];
    float fr2=ur[5], fi2=ui[5], fr3=ur[7], fi3=ui[7];
    dft4<SIGN>(er0,ei0, er1,ei1, er2,ei2, er3,ei3);
    dft4<SIGN>(fr0,fi0, fr1,fi1, fr2,fi2, fr3,fi3);
    {   const float c =  h, s_ = (SIGN<0) ? -h : h;
        cmul(fr1, fi1, c, s_); }
    {   float tr = fr2, ti = fi2;
        if (SIGN < 0){ fr2 =  ti; fi2 = -tr; }
        else         { fr2 = -ti; fi2 =  tr; }
    }
    {   const float c = -h, s_ = (SIGN<0) ? -h : h;
        cmul(fr3, fi3, c, s_); }
    ur[0]=er0+fr0; ui[0]=ei0+fi0;
    ur[1]=er1+fr1; ui[1]=ei1+fi1;
    ur[2]=er2+fr2; ui[2]=ei2+fi2;
    ur[3]=er3+fr3; ui[3]=ei3+fi3;
    ur[4]=er0-fr0; ui[4]=ei0-fi0;
    ur[5]=er1-fr1; ui[5]=ei1-fi1;
    ur[6]=er2-fr2; ui[6]=ei2-fi2;
    ur[7]=er3-fr3; ui[7]=ei3-fi3;
}

template<int SIGN>
__device__ __forceinline__ void twiddle8(float ur[8], float ui[8], float theta){
    float s, c;
    __sincosf(theta, &s, &c);
    const float wi = (SIGN < 0) ? -s : s;
    const float wr = c;
    float pr = wr, pi = wi;
    cmul(ur[1], ui[1], pr, pi);
#pragma unroll
    for (int m=2;m<8;m++){
        float nr = pr*wr - pi*wi;
        pi = pr*wi + pi*wr;
        pr = nr;
        cmul(ur[m], ui[m], pr, pi);
    }
}

// gain for spectral index k (0..2048) for BOTH rows at once (shared bg + gathers).
__device__ __forceinline__ void gain_pair(int k, const float* hhA, const float* hhB,
    float alpha, const float* __restrict__ P2w, const float* __restrict__ P2b,
    float& ga, float& gb){
    float nf = (float)k * (1.0f/2048.0f);
    float tt = nf * 5.0f;
    float lb = __expf(-0.5f * tt * tt);
    float hd = 0.5f / (1.0f + __expf(-(nf - 0.6f) * 10.0f));
    float bg = fmaxf(1.0f + lb - hd, 0.0f);
    float scaled = nf * 4095.0f;
    float fl = floorf(scaled);
    int lo = (int)fl;
    int hi = (int)ceilf(scaled);
    float fr = scaled - fl;
    const float4* p2lo = (const float4*)(P2w + (size_t)lo * RANK);
    const float4* p2hi = (const float4*)(P2w + (size_t)hi * RANK);
    float4 a0 = p2lo[0], a1 = p2lo[1];
    float4 b0 = p2hi[0], b1 = p2hi[1];
    float blo = P2b[lo], bhi = P2b[hi];
    float dAlo = blo + hhA[0]*a0.x + hhA[1]*a0.y + hhA[2]*a0.z + hhA[3]*a0.w
                     + hhA[4]*a1.x + hhA[5]*a1.y + hhA[6]*a1.z + hhA[7]*a1.w;
    float dAhi = bhi + hhA[0]*b0.x + hhA[1]*b0.y + hhA[2]*b0.z + hhA[3]*b0.w
                     + hhA[4]*b1.x + hhA[5]*b1.y + hhA[6]*b1.z + hhA[7]*b1.w;
    float dBlo = blo + hhB[0]*a0.x + hhB[1]*a0.y + hhB[2]*a0.z + hhB[3]*a0.w
                     + hhB[4]*a1.x + hhB[5]*a1.y + hhB[6]*a1.z + hhB[7]*a1.w;
    float dBhi = bhi + hhB[0]*b0.x + hhB[1]*b0.y + hhB[2]*b0.z + hhB[3]*b0.w
                     + hhB[4]*b1.x + hhB[5]*b1.y + hhB[6]*b1.z + hhB[7]*b1.w;
    float dA = dAlo + (dAhi - dAlo) * fr;
    float dB = dBlo + (dBhi - dBlo) * fr;
    ga = fmaxf(bg + alpha * dA, 0.0f);
    gb = fmaxf(bg + alpha * dB, 0.0f);
}

// ============================================================================
// REAL-PACKING STRUCTURE (2 rows per block, grid = 1024):
//  fwd:  W = FFT(x_a + i x_b)  (ONE complex FFT for two real rows)
//        Z_a[k] = (W[k]+conj(W[N-k]))/2,  Z_b[k] = (W[k]-conj(W[N-k]))/2i
//        (reconstructed on the fly from W[k],W[j] — never materialized)
//  gain: symmetric in k -> half-spectrum tables gA/gB[0..2048]; z pre-update
//        stays Hermitian so z_scaled[k] = g[min(k,N-k)] * Z[k].
//  inv:  out = Re(ifft(z)) = ifft(Herm(z)); Herm(z) = g*Z + (upd[k]+conj(upd[N-k]))/2.
//        Pack w2 = H_a + i H_b  -> ONE inverse FFT; Re -> row a, Im -> row b.
//        Each (k, N-k) pair is read+written by exactly ONE thread -> in-place.
//  Self-pairs k=0 / k=2048: H imaginary parts cancel exactly -> both write
//  formulas agree; k=2048 handled by thread 0 as an extra pair.
// FFT rounds are r4's verified code (layouts A/B/C, 520-pad, twiddles).
// VGPR wall (r2-r7 measured): pool ~256/SIMD, VGPR=64 -> 4 waves/SIMD; caps
// below 64 spill catastrophically. So: keep peak <= 64 (p/q split passes) and
// halve the WORK instead. LDS ~50KB -> 2-3 blocks/CU = the VGPR ceiling anyway.
// ============================================================================

__global__ __launch_bounds__(NT, 4) void recip_mixer(
    const float* __restrict__ x,
    const float* __restrict__ Ur, const float* __restrict__ Ui,
    const float* __restrict__ Vr, const float* __restrict__ Vi,
    const float* __restrict__ Wr, const float* __restrict__ Wi,
    const float* __restrict__ P1w, const float* __restrict__ P1b,
    const float* __restrict__ P2w, const float* __restrict__ P2b,
    const float* __restrict__ alphap,
    float* __restrict__ out)
{
    __shared__ float sre[BP], sim[BP];
    __shared__ float gA[NHALF], gB[NHALF];
    __shared__ float red[256];
    __shared__ float hidA[RANK], hidB[RANK];
    __shared__ float gamAr[RANK], gamAi[RANK], gamBr[RANK], gamBi[RANK];
    __shared__ float pqs[64];

    const int t    = threadIdx.x;
    const int pairidx = blockIdx.x;
    const int lane = t & 63;
    const int wid  = t >> 6;

    float ur[8], ui[8];

    const int baseA = (t & 63) + 512 * (t >> 6);
    const int baseB = (t & 7) + 8*(t >> 6) + 520*((t >> 3) & 7);
    const int baseC = (t >> 3) + 520*(t & 7);

    const float* xa = x + (size_t)(2 * pairidx) * S_LEN;
    const float* xb = xa + S_LEN;

    // ================= forward FFT of w = x_a + i x_b =================
    {
#pragma unroll
        for (int c=0;c<8;c++){ ur[c] = xa[t + 512*c]; ui[c] = xb[t + 512*c]; }
        dft8<-1>(ur, ui);
#pragma unroll
        for (int e=0;e<8;e++){ sre[baseA + 64*e] = ur[e]; sim[baseA + 64*e] = ui[e]; }
    }
    __syncthreads();
    {
#pragma unroll
        for (int m=0;m<8;m++){ ur[m] = sre[t + 512*m]; ui[m] = sim[t + 512*m]; }
        twiddle8<-1>(ur, ui, TWO_PI * (float)(t >> 6) * (1.0f/64.0f));
        dft8<-1>(ur, ui);
        __syncthreads();
#pragma unroll
        for (int e=0;e<8;e++){ sre[baseB + 64*e] = ur[e]; sim[baseB + 64*e] = ui[e]; }
    }
    __syncthreads();
    {
#pragma unroll
        for (int m=0;m<8;m++){ ur[m] = sre[t + 520*m]; ui[m] = sim[t + 520*m]; }
        twiddle8<-1>(ur, ui, TWO_PI * (float)(t >> 3) * (1.0f/512.0f));
        dft8<-1>(ur, ui);
        __syncthreads();
#pragma unroll
        for (int e=0;e<8;e++){ sre[baseC + 64*e] = ur[e]; sim[baseC + 64*e] = ui[e]; }
    }
    __syncthreads();
    {
#pragma unroll
        for (int m=0;m<8;m++){ ur[m] = sre[t + 520*m]; ui[m] = sim[t + 520*m]; }
        twiddle8<-1>(ur, ui, TWO_PI * (float)t * (1.0f/4096.0f));
        dft8<-1>(ur, ui);
        __syncthreads();
#pragma unroll
        for (int e=0;e<8;e++){ sre[t + 512*e] = ur[e]; sim[t + 512*e] = ui[e]; }
    }
    __syncthreads();   // phase 1 reads other threads' (k, N-k) slots

    // ===== phase 1: hidden for BOTH rows (z reconstructed from W on the fly)
    {
        float ha[RANK], hb[RANK];
#pragma unroll
        for (int r = 0; r < RANK; r++){ ha[r] = 0.0f; hb[r] = 0.0f; }
        for (int i = 0; i < PER; i++) {
            int k = t + NT * i;
            int j = (S_LEN - k) & (S_LEN - 1);
            float ar = sre[k], ai = sim[k];
            float br = sre[j], bi = sim[j];
            float zar = 0.5f*(ar + br), zai = 0.5f*(ai - bi);
            float zbr = 0.5f*(ai + bi), zbi = 0.5f*(br - ar);
#pragma unroll
            for (int r = 0; r < RANK; r++) {
                float p0 = P1w[r * (2 * S_LEN) + k];
                float p1 = P1w[r * (2 * S_LEN) + S_LEN + k];
                ha[r] += zar * p0 + zai * p1;
                hb[r] += zbr * p0 + zbi * p1;
            }
        }
#pragma unroll
        for (int r = 0; r < RANK; r++) {
#pragma unroll
            for (int off = 32; off > 0; off >>= 1){
                ha[r] += __shfl_xor(ha[r], off, 64);
                hb[r] += __shfl_xor(hb[r], off, 64);
            }
        }
        if (lane == 0) {
#pragma unroll
            for (int r = 0; r < RANK; r++){
                red[wid * 16 + r]     = ha[r];
                red[wid * 16 + 8 + r] = hb[r];
            }
        }
        __syncthreads();
        if (t < 16) {
            float v = 0.0f;
#pragma unroll
            for (int w = 0; w < 8; w++) v += red[w * 16 + t];
            float res = fmaxf(v + P1b[t & 7], 0.0f);
            if (t < 8) hidA[t] = res; else hidB[t - 8] = res;
        }
        __syncthreads();
    }

    // ===== phase 2a: half-spectrum gain tables gA/gB[0..2048]
    {
        float hhA[RANK], hhB[RANK];
#pragma unroll
        for (int r = 0; r < RANK; r++){ hhA[r] = hidA[r]; hhB[r] = hidB[r]; }
        const float alpha = alphap[0];
#pragma unroll
        for (int i = 0; i < 4; i++) {
            int k = t + 512 * i;           // 0..2047
            float ga, gb;
            gain_pair(k, hhA, hhB, alpha, P2w, P2b, ga, gb);
            gA[k] = ga; gB[k] = gb;
        }
        if (t == 0) {
            float ga, gb;
            gain_pair(2048, hhA, hhB, alpha, P2w, P2b, ga, gb);
            gA[2048] = ga; gB[2048] = gb;
        }
    }
    __syncthreads();   // 2b reads gA/gB at arbitrary m

    // ===== phase 2b p-pass: p for both rows (shared Ur/Ui loads)
    {
        float pAr[RANK], pAi[RANK], pBr[RANK], pBi[RANK];
#pragma unroll
        for (int r = 0; r < RANK; r++){ pAr[r]=0.f; pAi[r]=0.f; pBr[r]=0.f; pBi[r]=0.f; }
        for (int i = 0; i < PER; i++) {
            int k = t + NT * i;
            int j = (S_LEN - k) & (S_LEN - 1);
            int m = (k <= 2048) ? k : (S_LEN - k);
            float ar = sre[k], ai = sim[k];
            float br = sre[j], bi = sim[j];
            float ga = gA[m], gb = gB[m];
            float zar = 0.5f*ga*(ar + br), zai = 0.5f*ga*(ai - bi);
            float zbr = 0.5f*gb*(ai + bi), zbi = 0.5f*gb*(br - ar);
#pragma unroll
            for (int r = 0; r < RANK; r++) {
                float u_ = Ur[r * S_LEN + k], v_ = Ui[r * S_LEN + k];
                pAr[r] += zar * u_ - zai * v_;
                pAi[r] += zar * v_ + zai * u_;
                pBr[r] += zbr * u_ - zbi * v_;
                pBi[r] += zbr * v_ + zbi * u_;
            }
        }
#pragma unroll
        for (int r = 0; r < RANK; r++) {
#pragma unroll
            for (int off = 32; off > 0; off >>= 1) {
                pAr[r] += __shfl_xor(pAr[r], off, 64);
                pAi[r] += __shfl_xor(pAi[r], off, 64);
                pBr[r] += __shfl_xor(pBr[r], off, 64);
                pBi[r] += __shfl_xor(pBi[r], off, 64);
            }
        }
        if (lane == 0) {
#pragma unroll
            for (int r = 0; r < RANK; r++) {
                red[wid * 32 + r]      = pAr[r];
                red[wid * 32 + 8 + r]  = pAi[r];
                red[wid * 32 + 16 + r] = pBr[r];
                red[wid * 32 + 24 + r] = pBi[r];
            }
        }
        __syncthreads();
        if (t < 32) {
            float v = 0.0f;
#pragma unroll
            for (int w = 0; w < 8; w++) v += red[w * 32 + t];
            pqs[t] = v;
        }
        __syncthreads();
    }

    // ===== phase 2b q-pass: q for both rows (shared Vr/Vi loads), then gamma
    {
        float qAr[RANK], qAi[RANK], qBr[RANK], qBi[RANK];
#pragma unroll
        for (int r = 0; r < RANK; r++){ qAr[r]=0.f; qAi[r]=0.f; qBr[r]=0.f; qBi[r]=0.f; }
        for (int i = 0; i < PER; i++) {
            int k = t + NT * i;
            int j = (S_LEN - k) & (S_LEN - 1);
            int m = (k <= 2048) ? k : (S_LEN - k);
            float ar = sre[k], ai = sim[k];
            float br = sre[j], bi = sim[j];
            float ga = gA[m], gb = gB[m];
            float zar = 0.5f*ga*(ar + br), zai = 0.5f*ga*(ai - bi);
            float zbr = 0.5f*gb*(ai + bi), zbi = 0.5f*gb*(br - ar);
#pragma unroll
            for (int r = 0; r < RANK; r++) {
                float w_ = Vr[r * S_LEN + k], y_ = Vi[r * S_LEN + k];
                qAr[r] += zar * w_ - zai * y_;
                qAi[r] += zar * y_ + zai * w_;
                qBr[r] += zbr * w_ - zbi * y_;
                qBi[r] += zbr * y_ + zbi * w_;
            }
        }
#pragma unroll
        for (int r = 0; r < RANK; r++) {
#pragma unroll
            for (int off = 32; off > 0; off >>= 1) {
                qAr[r] += __shfl_xor(qAr[r], off, 64);
                qAi[r] += __shfl_xor(qAi[r], off, 64);
                qBr[r] += __shfl_xor(qBr[r], off, 64);
                qBi[r] += __shfl_xor(qBi[r], off, 64);
            }
        }
        if (lane == 0) {
#pragma unroll
            for (int r = 0; r < RANK; r++) {
                red[wid * 32 + r]      = qAr[r];
                red[wid * 32 + 8 + r]  = qAi[r];
                red[wid * 32 + 16 + r] = qBr[r];
                red[wid * 32 + 24 + r] = qBi[r];
            }
        }
        __syncthreads();
        if (t < 32) {
            float v = 0.0f;
#pragma unroll
            for (int w = 0; w < 8; w++) v += red[w * 32 + t];
            pqs[32 + t] = v;
        }
        __syncthreads();
        if (t < 8) {
            float paR = pqs[t],      paI = pqs[8 + t];
            float pbR = pqs[16 + t], pbI = pqs[24 + t];
            float qaR = pqs[32 + t], qaI = pqs[40 + t];
            float qbR = pqs[48 + t], qbI = pqs[56 + t];
            gamAr[t] = paR * qaR + paI * qaI;   // Re(p * conj(q)) row a
            gamAi[t] = paI * qaR - paR * qaI;
            gamBr[t] = pbR * qbR + pbI * qbI;   // row b
            gamBi[t] = pbI * qbR - pbR * qbI;
        }
        __syncthreads();
    }

    // ===== phase H: z += upd, take Hermitian part, pack w2 = H_a + i H_b.
    // Each thread owns pairs (k, N-k): reads W[k],W[j], writes w2[k],w2[j].
    {
#define UPD_TERM(WKR, WKI, WJR, WJI, R) { \
        float gar = gamAr[R], gai = gamAi[R]; \
        float gbr = gamBr[R], gbi = gamBi[R]; \
        uakr += gar*(WKR) - gai*(WKI); uaki += gar*(WKI) + gai*(WKR); \
        uajr += gar*(WJR) - gai*(WJI); uaji += gar*(WJI) + gai*(WJR); \
        ubkr += gbr*(WKR) - gbi*(WKI); ubki += gbr*(WKI) + gbi*(WKR); \
        ubjr += gbr*(WJR) - gbi*(WJI); ubji += gbr*(WJI) + gbi*(WJR); }

        auto do_pair = [&](int k){
            int j = (S_LEN - k) & (S_LEN - 1);
            float ar = sre[k], ai = sim[k];
            float br = sre[j], bi = sim[j];
            float ga = gA[k], gb = gB[k];      // k <= 2048 here
            float zar = 0.5f*ga*(ar + br), zai = 0.5f*ga*(ai - bi);
            float zbr = 0.5f*gb*(ai + bi), zbi = 0.5f*gb*(br - ar);
            float uakr=0.f, uaki=0.f, uajr=0.f, uaji=0.f;
            float ubkr=0.f, ubki=0.f, ubjr=0.f, ubji=0.f;
            const float4* WRk = (const float4*)(Wr + (size_t)k * RANK);
            const float4* WIk = (const float4*)(Wi + (size_t)k * RANK);
            const float4* WRj = (const float4*)(Wr + (size_t)j * RANK);
            const float4* WIj = (const float4*)(Wi + (size_t)j * RANK);
            {
                float4 kr = WRk[0], ki = WIk[0], jr = WRj[0], ji = WIj[0];
                UPD_TERM(kr.x, ki.x, jr.x, ji.x, 0)
                UPD_TERM(kr.y, ki.y, jr.y, ji.y, 1)
                UPD_TERM(kr.z, ki.z, jr.z, ji.z, 2)
                UPD_TERM(kr.w, ki.w, jr.w, ji.w, 3)
            }
            {
                float4 kr = WRk[1], ki = WIk[1], jr = WRj[1], ji = WIj[1];
                UPD_TERM(kr.x, ki.x, jr.x, ji.x, 4)
                UPD_TERM(kr.y, ki.y, jr.y, ji.y, 5)
                UPD_TERM(kr.z, ki.z, jr.z, ji.z, 6)
                UPD_TERM(kr.w, ki.w, jr.w, ji.w, 7)
            }
            float HaR = zar + 0.5f*(uakr + uajr);
            float HaI = zai + 0.5f*(uaki - uaji);
            float HbR = zbr + 0.5f*(ubkr + ubjr);
            float HbI = zbi + 0.5f*(ubki - ubji);
            sre[k] = HaR - HbI;  sim[k] = HaI + HbR;
            sre[j] = HaR + HbI;  sim[j] = HbR - HaI;
        };
#pragma unroll
        for (int i = 0; i < 4; i++) do_pair(t + 512 * i);   // k = 0..2047
        if (t == 0) do_pair(2048);                          // self-pair
#undef UPD_TERM
    }
    __syncthreads();   // all w2 written before inverse FFT reads

    // ================= inverse FFT: out_a = Re, out_b = Im =================
    {
#pragma unroll
        for (int c=0;c<8;c++){ ur[c] = sre[t + 512*c]; ui[c] = sim[t + 512*c]; }
        dft8<1>(ur, ui);
        __syncthreads();   // w2 consumed before A overwrites
#pragma unroll
        for (int e=0;e<8;e++){ sre[baseA + 64*e] = ur[e]; sim[baseA + 64*e] = ui[e]; }
    }
    __syncthreads();
    {
#pragma unroll
        for (int m=0;m<8;m++){ ur[m] = sre[t + 512*m]; ui[m] = sim[t + 512*m]; }
        twiddle8<1>(ur, ui, TWO_PI * (float)(t >> 6) * (1.0f/64.0f));
        dft8<1>(ur, ui);
        __syncthreads();
#pragma unroll
        for (int e=0;e<8;e++){ sre[baseB + 64*e] = ur[e]; sim[baseB + 64*e] = ui[e]; }
    }
    __syncthreads();
    {
#pragma unroll
        for (int m=0;m<8;m++){ ur[m] = sre[t + 520*m]; ui[m] = sim[t + 520*m]; }
        twiddle8<1>(ur, ui, TWO_PI * (float)(t >> 3) * (1.0f/512.0f));
        dft8<1>(ur, ui);
        __syncthreads();
#pragma unroll
        for (int e=0;e<8;e++){ sre[baseC + 64*e] = ur[e]; sim[baseC + 64*e] = ui[e]; }
    }
    __syncthreads();
    {
#pragma unroll
        for (int m=0;m<8;m++){ ur[m] = sre[t + 520*m]; ui[m] = sim[t + 520*m]; }
        twiddle8<1>(ur, ui, TWO_PI * (float)t * (1.0f/4096.0f));
        dft8<1>(ur, ui);
        float* orow_a = out + (size_t)(2 * pairidx) * S_LEN;
        float* orow_b = orow_a + S_LEN;
        const float scale = 1.0f / (float)S_LEN;
#pragma unroll
        for (int e=0;e<8;e++){
            orow_a[t + 512*e] = ur[e] * scale;   // Re -> row a
            orow_b[t + 512*e] = ui[e] * scale;   // Im -> row b
        }
    }
}

extern "C" void kernel_launch(void* const* d_in, const int* in_sizes, int n_in,
                              void* d_out, int out_size, void* d_ws, size_t ws_size,
                              hipStream_t stream) {
    const float* x    = (const float*)d_in[0];
    const float* Ur   = (const float*)d_in[1];
    const float* Ui   = (const float*)d_in[2];
    const float* Vr   = (const float*)d_in[3];
    const float* Vi   = (const float*)d_in[4];
    const float* Wr   = (const float*)d_in[5];
    const float* Wi   = (const float*)d_in[6];
    const float* P1w  = (const float*)d_in[7];
    const float* P1b  = (const float*)d_in[8];
    const float* P2w  = (const float*)d_in[9];
    const float* P2b  = (const float*)d_in[10];
    const float* alph = (const float*)d_in[11];

    recip_mixer<<<dim3(1024), dim3(NT), 0, stream>>>(
        x, Ur, Ui, Vr, Vi, Wr, Wi, P1w, P1b, P2w, P2b, alph, (float*)d_out);
}

// Round 9
// 213.709 us; speedup vs baseline: 1.6024x; 1.0004x over previous
//
#include <hip/hip_runtime.h>

#define S_LEN 4096
#define NT 512
#define PER 8
#define RANK 8
#define BP 4160      // padded FFT buffer float count (max transpose addr 4151)
#define NHALF 2049   // half-spectrum gain table (k = 0..2048)
#define TWO_PI 6.2831853071795864769f

__device__ __forceinline__ void cmul(float& xr, float& xi, float cr, float ci){
    float tr = xr*cr - xi*ci;
    xi = xr*ci + xi*cr;
    xr = tr;
}

// 4-point DFT, in place. SIGN=-1 forward, SIGN=+1 inverse.
template<int SIGN>
__device__ __forceinline__ void dft4(float& ar,float& ai,float& br,float& bi,
                                     float& cr,float& ci,float& dr,float& di){
    float Ar=ar+cr, Ai=ai+ci;
    float Br=ar-cr, Bi=ai-ci;
    float Cr=br+dr, Ci=bi+di;
    float Dr, Di;
    if (SIGN < 0){ Dr = bi-di; Di = dr-br; }
    else         { Dr = di-bi; Di = br-dr; }
    ar=Ar+Cr; ai=Ai+Ci;
    br=Br+Dr; bi=Bi+Di;
    cr=Ar-Cr; ci=Ai-Ci;
    dr=Br-Dr; di=Bi-Di;
}

// 8-point DFT in registers, natural-order in and out.
template<int SIGN>
__device__ __forceinline__ void dft8(float ur[8], float ui[8]){
    const float h = 0.70710678118654752f;
    float er0=ur[0], ei0=ui[0], er1=ur[2], ei1=ui[2];
    float er2=ur[4], ei2=ui[4], er3=ur[6], ei3=ui[6];
    float fr0=ur[1], fi0=ui[1], fr1=ur[3], fi1=ui[3];
    float fr2=ur[5], fi2=ui[5], fr3=ur[7], fi3=ui[7];
    dft4<SIGN>(er0,ei0, er1,ei1, er2,ei2, er3,ei3);
    dft4<SIGN>(fr0,fi0, fr1,fi1, fr2,fi2, fr3,fi3);
    {   const float c =  h, s_ = (SIGN<0) ? -h : h;
        cmul(fr1, fi1, c, s_); }
    {   float tr = fr2, ti = fi2;
        if (SIGN < 0){ fr2 =  ti; fi2 = -tr; }
        else         { fr2 = -ti; fi2 =  tr; }
    }
    {   const float c = -h, s_ = (SIGN<0) ? -h : h;
        cmul(fr3, fi3, c, s_); }
    ur[0]=er0+fr0; ui[0]=ei0+fi0;
    ur[1]=er1+fr1; ui[1]=ei1+fi1;
    ur[2]=er2+fr2; ui[2]=ei2+fi2;
    ur[3]=er3+fr3; ui[3]=ei3+fi3;
    ur[4]=er0-fr0; ui[4]=ei0-fi0;
    ur[5]=er1-fr1; ui[5]=ei1-fi1;
    ur[6]=er2-fr2; ui[6]=ei2-fi2;
    ur[7]=er3-fr3; ui[7]=ei3-fi3;
}

template<int SIGN>
__device__ __forceinline__ void twiddle8(float ur[8], float ui[8], float theta){
    float s, c;
    __sincosf(theta, &s, &c);
    const float wi = (SIGN < 0) ? -s : s;
    const float wr = c;
    float pr = wr, pi = wi;
    cmul(ur[1], ui[1], pr, pi);
#pragma unroll
    for (int m=2;m<8;m++){
        float nr = pr*wr - pi*wi;
        pi = pr*wi + pi*wr;
        pr = nr;
        cmul(ur[m], ui[m], pr, pi);
    }
}

// gain for spectral index k (0..2048) for BOTH rows at once (shared bg + gathers).
__device__ __forceinline__ void gain_pair(int k, const float* hhA, const float* hhB,
    float alpha, const float* __restrict__ P2w, const float* __restrict__ P2b,
    float& ga, float& gb){
    float nf = (float)k * (1.0f/2048.0f);
    float tt = nf * 5.0f;
    float lb = __expf(-0.5f * tt * tt);
    float hd = 0.5f / (1.0f + __expf(-(nf - 0.6f) * 10.0f));
    float bg = fmaxf(1.0f + lb - hd, 0.0f);
    float scaled = nf * 4095.0f;
    float fl = floorf(scaled);
    int lo = (int)fl;
    int hi = (int)ceilf(scaled);
    float fr = scaled - fl;
    const float4* p2lo = (const float4*)(P2w + (size_t)lo * RANK);
    const float4* p2hi = (const float4*)(P2w + (size_t)hi * RANK);
    float4 a0 = p2lo[0], a1 = p2lo[1];
    float4 b0 = p2hi[0], b1 = p2hi[1];
    float blo = P2b[lo], bhi = P2b[hi];
    float dAlo = blo + hhA[0]*a0.x + hhA[1]*a0.y + hhA[2]*a0.z + hhA[3]*a0.w
                     + hhA[4]*a1.x + hhA[5]*a1.y + hhA[6]*a1.z + hhA[7]*a1.w;
    float dAhi = bhi + hhA[0]*b0.x + hhA[1]*b0.y + hhA[2]*b0.z + hhA[3]*b0.w
                     + hhA[4]*b1.x + hhA[5]*b1.y + hhA[6]*b1.z + hhA[7]*b1.w;
    float dBlo = blo + hhB[0]*a0.x + hhB[1]*a0.y + hhB[2]*a0.z + hhB[3]*a0.w
                     + hhB[4]*a1.x + hhB[5]*a1.y + hhB[6]*a1.z + hhB[7]*a1.w;
    float dBhi = bhi + hhB[0]*b0.x + hhB[1]*b0.y + hhB[2]*b0.z + hhB[3]*b0.w
                     + hhB[4]*b1.x + hhB[5]*b1.y + hhB[6]*b1.z + hhB[7]*b1.w;
    float dA = dAlo + (dAhi - dAlo) * fr;
    float dB = dBlo + (dBhi - dBlo) * fr;
    ga = fmaxf(bg + alpha * dA, 0.0f);
    gb = fmaxf(bg + alpha * dB, 0.0f);
}

// ============================================================================
// REAL-PACKING STRUCTURE (2 rows per block, grid = 1024) — r8, passing.
// r9 change: phase H de-pressurized. r8's do_pair held 8 accum + 16 W regs
// + temps (~70 live > 64 cap) -> 44MB scratch WRITE + 20MB scratch FETCH.
// Now: (a) k-point update fully computed BEFORE any W[j] load (max 2 live
// float4 operands), (b) gammas packed as float4 gam4[8] -> ds_read_b128
// broadcast (16 reads/pair vs 64 scalar). Peak ~45-50 < 64 -> no spill.
// VGPR wall (r2-r7 measured): pool ~256/SIMD; VGPR=64 -> 4 waves/SIMD;
// caps < 64 spill catastrophically. Keep peak under 64, halve WORK instead.
// ============================================================================

__global__ __launch_bounds__(NT, 4) void recip_mixer(
    const float* __restrict__ x,
    const float* __restrict__ Ur, const float* __restrict__ Ui,
    const float* __restrict__ Vr, const float* __restrict__ Vi,
    const float* __restrict__ Wr, const float* __restrict__ Wi,
    const float* __restrict__ P1w, const float* __restrict__ P1b,
    const float* __restrict__ P2w, const float* __restrict__ P2b,
    const float* __restrict__ alphap,
    float* __restrict__ out)
{
    __shared__ float sre[BP], sim[BP];
    __shared__ float gA[NHALF], gB[NHALF];
    __shared__ float red[256];
    __shared__ float hidA[RANK], hidB[RANK];
    __shared__ float4 gam4[RANK];   // {gamAr, gamAi, gamBr, gamBi} per r
    __shared__ float pqs[64];

    const int t    = threadIdx.x;
    const int pairidx = blockIdx.x;
    const int lane = t & 63;
    const int wid  = t >> 6;

    float ur[8], ui[8];

    const int baseA = (t & 63) + 512 * (t >> 6);
    const int baseB = (t & 7) + 8*(t >> 6) + 520*((t >> 3) & 7);
    const int baseC = (t >> 3) + 520*(t & 7);

    const float* xa = x + (size_t)(2 * pairidx) * S_LEN;
    const float* xb = xa + S_LEN;

    // ================= forward FFT of w = x_a + i x_b =================
    {
#pragma unroll
        for (int c=0;c<8;c++){ ur[c] = xa[t + 512*c]; ui[c] = xb[t + 512*c]; }
        dft8<-1>(ur, ui);
#pragma unroll
        for (int e=0;e<8;e++){ sre[baseA + 64*e] = ur[e]; sim[baseA + 64*e] = ui[e]; }
    }
    __syncthreads();
    {
#pragma unroll
        for (int m=0;m<8;m++){ ur[m] = sre[t + 512*m]; ui[m] = sim[t + 512*m]; }
        twiddle8<-1>(ur, ui, TWO_PI * (float)(t >> 6) * (1.0f/64.0f));
        dft8<-1>(ur, ui);
        __syncthreads();
#pragma unroll
        for (int e=0;e<8;e++){ sre[baseB + 64*e] = ur[e]; sim[baseB + 64*e] = ui[e]; }
    }
    __syncthreads();
    {
#pragma unroll
        for (int m=0;m<8;m++){ ur[m] = sre[t + 520*m]; ui[m] = sim[t + 520*m]; }
        twiddle8<-1>(ur, ui, TWO_PI * (float)(t >> 3) * (1.0f/512.0f));
        dft8<-1>(ur, ui);
        __syncthreads();
#pragma unroll
        for (int e=0;e<8;e++){ sre[baseC + 64*e] = ur[e]; sim[baseC + 64*e] = ui[e]; }
    }
    __syncthreads();
    {
#pragma unroll
        for (int m=0;m<8;m++){ ur[m] = sre[t + 520*m]; ui[m] = sim[t + 520*m]; }
        twiddle8<-1>(ur, ui, TWO_PI * (float)t * (1.0f/4096.0f));
        dft8<-1>(ur, ui);
        __syncthreads();
#pragma unroll
        for (int e=0;e<8;e++){ sre[t + 512*e] = ur[e]; sim[t + 512*e] = ui[e]; }
    }
    __syncthreads();   // phase 1 reads other threads' (k, N-k) slots

    // ===== phase 1: hidden for BOTH rows (z reconstructed from W on the fly)
    {
        float ha[RANK], hb[RANK];
#pragma unroll
        for (int r = 0; r < RANK; r++){ ha[r] = 0.0f; hb[r] = 0.0f; }
        for (int i = 0; i < PER; i++) {
            int k = t + NT * i;
            int j = (S_LEN - k) & (S_LEN - 1);
            float ar = sre[k], ai = sim[k];
            float br = sre[j], bi = sim[j];
            float zar = 0.5f*(ar + br), zai = 0.5f*(ai - bi);
            float zbr = 0.5f*(ai + bi), zbi = 0.5f*(br - ar);
#pragma unroll
            for (int r = 0; r < RANK; r++) {
                float p0 = P1w[r * (2 * S_LEN) + k];
                float p1 = P1w[r * (2 * S_LEN) + S_LEN + k];
                ha[r] += zar * p0 + zai * p1;
                hb[r] += zbr * p0 + zbi * p1;
            }
        }
#pragma unroll
        for (int r = 0; r < RANK; r++) {
#pragma unroll
            for (int off = 32; off > 0; off >>= 1){
                ha[r] += __shfl_xor(ha[r], off, 64);
                hb[r] += __shfl_xor(hb[r], off, 64);
            }
        }
        if (lane == 0) {
#pragma unroll
            for (int r = 0; r < RANK; r++){
                red[wid * 16 + r]     = ha[r];
                red[wid * 16 + 8 + r] = hb[r];
            }
        }
        __syncthreads();
        if (t < 16) {
            float v = 0.0f;
#pragma unroll
            for (int w = 0; w < 8; w++) v += red[w * 16 + t];
            float res = fmaxf(v + P1b[t & 7], 0.0f);
            if (t < 8) hidA[t] = res; else hidB[t - 8] = res;
        }
        __syncthreads();
    }

    // ===== phase 2a: half-spectrum gain tables gA/gB[0..2048]
    {
        float hhA[RANK], hhB[RANK];
#pragma unroll
        for (int r = 0; r < RANK; r++){ hhA[r] = hidA[r]; hhB[r] = hidB[r]; }
        const float alpha = alphap[0];
#pragma unroll
        for (int i = 0; i < 4; i++) {
            int k = t + 512 * i;           // 0..2047
            float ga, gb;
            gain_pair(k, hhA, hhB, alpha, P2w, P2b, ga, gb);
            gA[k] = ga; gB[k] = gb;
        }
        if (t == 0) {
            float ga, gb;
            gain_pair(2048, hhA, hhB, alpha, P2w, P2b, ga, gb);
            gA[2048] = ga; gB[2048] = gb;
        }
    }
    __syncthreads();   // 2b reads gA/gB at arbitrary m

    // ===== phase 2b p-pass: p for both rows (shared Ur/Ui loads)
    {
        float pAr[RANK], pAi[RANK], pBr[RANK], pBi[RANK];
#pragma unroll
        for (int r = 0; r < RANK; r++){ pAr[r]=0.f; pAi[r]=0.f; pBr[r]=0.f; pBi[r]=0.f; }
        for (int i = 0; i < PER; i++) {
            int k = t + NT * i;
            int j = (S_LEN - k) & (S_LEN - 1);
            int m = (k <= 2048) ? k : (S_LEN - k);
            float ar = sre[k], ai = sim[k];
            float br = sre[j], bi = sim[j];
            float ga = gA[m], gb = gB[m];
            float zar = 0.5f*ga*(ar + br), zai = 0.5f*ga*(ai - bi);
            float zbr = 0.5f*gb*(ai + bi), zbi = 0.5f*gb*(br - ar);
#pragma unroll
            for (int r = 0; r < RANK; r++) {
                float u_ = Ur[r * S_LEN + k], v_ = Ui[r * S_LEN + k];
                pAr[r] += zar * u_ - zai * v_;
                pAi[r] += zar * v_ + zai * u_;
                pBr[r] += zbr * u_ - zbi * v_;
                pBi[r] += zbr * v_ + zbi * u_;
            }
        }
#pragma unroll
        for (int r = 0; r < RANK; r++) {
#pragma unroll
            for (int off = 32; off > 0; off >>= 1) {
                pAr[r] += __shfl_xor(pAr[r], off, 64);
                pAi[r] += __shfl_xor(pAi[r], off, 64);
                pBr[r] += __shfl_xor(pBr[r], off, 64);
                pBi[r] += __shfl_xor(pBi[r], off, 64);
            }
        }
        if (lane == 0) {
#pragma unroll
            for (int r = 0; r < RANK; r++) {
                red[wid * 32 + r]      = pAr[r];
                red[wid * 32 + 8 + r]  = pAi[r];
                red[wid * 32 + 16 + r] = pBr[r];
                red[wid * 32 + 24 + r] = pBi[r];
            }
        }
        __syncthreads();
        if (t < 32) {
            float v = 0.0f;
#pragma unroll
            for (int w = 0; w < 8; w++) v += red[w * 32 + t];
            pqs[t] = v;
        }
        __syncthreads();
    }

    // ===== phase 2b q-pass: q for both rows (shared Vr/Vi loads), then gamma
    {
        float qAr[RANK], qAi[RANK], qBr[RANK], qBi[RANK];
#pragma unroll
        for (int r = 0; r < RANK; r++){ qAr[r]=0.f; qAi[r]=0.f; qBr[r]=0.f; qBi[r]=0.f; }
        for (int i = 0; i < PER; i++) {
            int k = t + NT * i;
            int j = (S_LEN - k) & (S_LEN - 1);
            int m = (k <= 2048) ? k : (S_LEN - k);
            float ar = sre[k], ai = sim[k];
            float br = sre[j], bi = sim[j];
            float ga = gA[m], gb = gB[m];
            float zar = 0.5f*ga*(ar + br), zai = 0.5f*ga*(ai - bi);
            float zbr = 0.5f*gb*(ai + bi), zbi = 0.5f*gb*(br - ar);
#pragma unroll
            for (int r = 0; r < RANK; r++) {
                float w_ = Vr[r * S_LEN + k], y_ = Vi[r * S_LEN + k];
                qAr[r] += zar * w_ - zai * y_;
                qAi[r] += zar * y_ + zai * w_;
                qBr[r] += zbr * w_ - zbi * y_;
                qBi[r] += zbr * y_ + zbi * w_;
            }
        }
#pragma unroll
        for (int r = 0; r < RANK; r++) {
#pragma unroll
            for (int off = 32; off > 0; off >>= 1) {
                qAr[r] += __shfl_xor(qAr[r], off, 64);
                qAi[r] += __shfl_xor(qAi[r], off, 64);
                qBr[r] += __shfl_xor(qBr[r], off, 64);
                qBi[r] += __shfl_xor(qBi[r], off, 64);
            }
        }
        if (lane == 0) {
#pragma unroll
            for (int r = 0; r < RANK; r++) {
                red[wid * 32 + r]      = qAr[r];
                red[wid * 32 + 8 + r]  = qAi[r];
                red[wid * 32 + 16 + r] = qBr[r];
                red[wid * 32 + 24 + r] = qBi[r];
            }
        }
        __syncthreads();
        if (t < 32) {
            float v = 0.0f;
#pragma unroll
            for (int w = 0; w < 8; w++) v += red[w * 32 + t];
            pqs[32 + t] = v;
        }
        __syncthreads();
        if (t < 8) {
            float paR = pqs[t],      paI = pqs[8 + t];
            float pbR = pqs[16 + t], pbI = pqs[24 + t];
            float qaR = pqs[32 + t], qaI = pqs[40 + t];
            float qbR = pqs[48 + t], qbI = pqs[56 + t];
            gam4[t] = make_float4(
                paR * qaR + paI * qaI,    // gamAr = Re(p_a conj(q_a))
                paI * qaR - paR * qaI,    // gamAi
                pbR * qbR + pbI * qbI,    // gamBr
                pbI * qbR - pbR * qbI);   // gamBi
        }
        __syncthreads();
    }

    // ===== phase H: z += upd, Hermitian part, pack w2 = H_a + i H_b.
    // Register-lean: finish the k-point (2 float4 operands live) before
    // touching W[j]; gammas via b128 broadcast from gam4.
    {
        auto do_pair = [&](int k){
            int j = (S_LEN - k) & (S_LEN - 1);
            float ar = sre[k], ai = sim[k];
            float br = sre[j], bi = sim[j];
            float ga = gA[k], gb = gB[k];      // k <= 2048 here
            float zar = 0.5f*ga*(ar + br), zai = 0.5f*ga*(ai - bi);
            float zbr = 0.5f*gb*(ai + bi), zbi = 0.5f*gb*(br - ar);

            float uakr=0.f, uaki=0.f, ubkr=0.f, ubki=0.f;
            {
                const float4* WRk = (const float4*)(Wr + (size_t)k * RANK);
                const float4* WIk = (const float4*)(Wi + (size_t)k * RANK);
#pragma unroll
                for (int h2 = 0; h2 < 2; ++h2){
                    float4 w4 = WRk[h2], y4 = WIk[h2];
                    float4 g0 = gam4[4*h2+0];
                    uakr += g0.x*w4.x - g0.y*y4.x;  uaki += g0.x*y4.x + g0.y*w4.x;
                    ubkr += g0.z*w4.x - g0.w*y4.x;  ubki += g0.z*y4.x + g0.w*w4.x;
                    float4 g1 = gam4[4*h2+1];
                    uakr += g1.x*w4.y - g1.y*y4.y;  uaki += g1.x*y4.y + g1.y*w4.y;
                    ubkr += g1.z*w4.y - g1.w*y4.y;  ubki += g1.z*y4.y + g1.w*w4.y;
                    float4 g2 = gam4[4*h2+2];
                    uakr += g2.x*w4.z - g2.y*y4.z;  uaki += g2.x*y4.z + g2.y*w4.z;
                    ubkr += g2.z*w4.z - g2.w*y4.z;  ubki += g2.z*y4.z + g2.w*w4.z;
                    float4 g3 = gam4[4*h2+3];
                    uakr += g3.x*w4.w - g3.y*y4.w;  uaki += g3.x*y4.w + g3.y*w4.w;
                    ubkr += g3.z*w4.w - g3.w*y4.w;  ubki += g3.z*y4.w + g3.w*w4.w;
                }
            }
            float uajr=0.f, uaji=0.f, ubjr=0.f, ubji=0.f;
            {
                const float4* WRj = (const float4*)(Wr + (size_t)j * RANK);
                const float4* WIj = (const float4*)(Wi + (size_t)j * RANK);
#pragma unroll
                for (int h2 = 0; h2 < 2; ++h2){
                    float4 w4 = WRj[h2], y4 = WIj[h2];
                    float4 g0 = gam4[4*h2+0];
                    uajr += g0.x*w4.x - g0.y*y4.x;  uaji += g0.x*y4.x + g0.y*w4.x;
                    ubjr += g0.z*w4.x - g0.w*y4.x;  ubji += g0.z*y4.x + g0.w*w4.x;
                    float4 g1 = gam4[4*h2+1];
                    uajr += g1.x*w4.y - g1.y*y4.y;  uaji += g1.x*y4.y + g1.y*w4.y;
                    ubjr += g1.z*w4.y - g1.w*y4.y;  ubji += g1.z*y4.y + g1.w*w4.y;
                    float4 g2 = gam4[4*h2+2];
                    uajr += g2.x*w4.z - g2.y*y4.z;  uaji += g2.x*y4.z + g2.y*w4.z;
                    ubjr += g2.z*w4.z - g2.w*y4.z;  ubji += g2.z*y4.z + g2.w*w4.z;
                    float4 g3 = gam4[4*h2+3];
                    uajr += g3.x*w4.w - g3.y*y4.w;  uaji += g3.x*y4.w + g3.y*w4.w;
                    ubjr += g3.z*w4.w - g3.w*y4.w;  ubji += g3.z*y4.w + g3.w*w4.w;
                }
            }
            float HaR = zar + 0.5f*(uakr + uajr);
            float HaI = zai + 0.5f*(uaki - uaji);
            float HbR = zbr + 0.5f*(ubkr + ubjr);
            float HbI = zbi + 0.5f*(ubki - ubji);
            sre[k] = HaR - HbI;  sim[k] = HaI + HbR;
            sre[j] = HaR + HbI;  sim[j] = HbR - HaI;
        };
#pragma unroll
        for (int i = 0; i < 4; i++) do_pair(t + 512 * i);   // k = 0..2047
        if (t == 0) do_pair(2048);                          // self-pair
    }
    __syncthreads();   // all w2 written before inverse FFT reads

    // ================= inverse FFT: out_a = Re, out_b = Im =================
    {
#pragma unroll
        for (int c=0;c<8;c++){ ur[c] = sre[t + 512*c]; ui[c] = sim[t + 512*c]; }
        dft8<1>(ur, ui);
        __syncthreads();   // w2 consumed before A overwrites
#pragma unroll
        for (int e=0;e<8;e++){ sre[baseA + 64*e] = ur[e]; sim[baseA + 64*e] = ui[e]; }
    }
    __syncthreads();
    {
#pragma unroll
        for (int m=0;m<8;m++){ ur[m] = sre[t + 512*m]; ui[m] = sim[t + 512*m]; }
        twiddle8<1>(ur, ui, TWO_PI * (float)(t >> 6) * (1.0f/64.0f));
        dft8<1>(ur, ui);
        __syncthreads();
#pragma unroll
        for (int e=0;e<8;e++){ sre[baseB + 64*e] = ur[e]; sim[baseB + 64*e] = ui[e]; }
    }
    __syncthreads();
    {
#pragma unroll
        for (int m=0;m<8;m++){ ur[m] = sre[t + 520*m]; ui[m] = sim[t + 520*m]; }
        twiddle8<1>(ur, ui, TWO_PI * (float)(t >> 3) * (1.0f/512.0f));
        dft8<1>(ur, ui);
        __syncthreads();
#pragma unroll
        for (int e=0;e<8;e++){ sre[baseC + 64*e] = ur[e]; sim[baseC + 64*e] = ui[e]; }
    }
    __syncthreads();
    {
#pragma unroll
        for (int m=0;m<8;m++){ ur[m] = sre[t + 520*m]; ui[m] = sim[t + 520*m]; }
        twiddle8<1>(ur, ui, TWO_PI * (float)t * (1.0f/4096.0f));
        dft8<1>(ur, ui);
        float* orow_a = out + (size_t)(2 * pairidx) * S_LEN;
        float* orow_b = orow_a + S_LEN;
        const float scale = 1.0f / (float)S_LEN;
#pragma unroll
        for (int e=0;e<8;e++){
            orow_a[t + 512*e] = ur[e] * scale;   // Re -> row a
            orow_b[t + 512*e] = ui[e] * scale;   // Im -> row b
        }
    }
}

extern "C" void kernel_launch(void* const* d_in, const int* in_sizes, int n_in,
                              void* d_out, int out_size, void* d_ws, size_t ws_size,
                              hipStream_t stream) {
    const float* x    = (const float*)d_in[0];
    const float* Ur   = (const float*)d_in[1];
    const float* Ui   = (const float*)d_in[2];
    const float* Vr   = (const float*)d_in[3];
    const float* Vi   = (const float*)d_in[4];
    const float* Wr   = (const float*)d_in[5];
    const float* Wi   = (const float*)d_in[6];
    const float* P1w  = (const float*)d_in[7];
    const float* P1b  = (const float*)d_in[8];
    const float* P2w  = (const float*)d_in[9];
    const float* P2b  = (const float*)d_in[10];
    const float* alph = (const float*)d_in[11];

    recip_mixer<<<dim3(1024), dim3(NT), 0, stream>>>(
        x, Ur, Ui, Vr, Vi, Wr, Wi, P1w, P1b, P2w, P2b, alph, (float*)d_out);
}

// Round 10
// 193.388 us; speedup vs baseline: 1.7708x; 1.1051x over previous
//
#include <hip/hip_runtime.h>

#define S_LEN 4096
#define NT 512
#define PER 8
#define RANK 8
#define BP 4160      // padded FFT buffer float count (max transpose addr 4151)
#define NHALF 2049   // half-spectrum gain table (k = 0..2048)
#define TWO_PI 6.2831853071795864769f

__device__ __forceinline__ void cmul(float& xr, float& xi, float cr, float ci){
    float tr = xr*cr - xi*ci;
    xi = xr*ci + xi*cr;
    xr = tr;
}

// 4-point DFT, in place. SIGN=-1 forward, SIGN=+1 inverse.
template<int SIGN>
__device__ __forceinline__ void dft4(float& ar,float& ai,float& br,float& bi,
                                     float& cr,float& ci,float& dr,float& di){
    float Ar=ar+cr, Ai=ai+ci;
    float Br=ar-cr, Bi=ai-ci;
    float Cr=br+dr, Ci=bi+di;
    float Dr, Di;
    if (SIGN < 0){ Dr = bi-di; Di = dr-br; }
    else         { Dr = di-bi; Di = br-dr; }
    ar=Ar+Cr; ai=Ai+Ci;
    br=Br+Dr; bi=Bi+Di;
    cr=Ar-Cr; ci=Ai-Ci;
    dr=Br-Dr; di=Bi-Di;
}

// 8-point DFT in registers, natural-order in and out.
template<int SIGN>
__device__ __forceinline__ void dft8(float ur[8], float ui[8]){
    const float h = 0.70710678118654752f;
    float er0=ur[0], ei0=ui[0], er1=ur[2], ei1=ui[2];
    float er2=ur[4], ei2=ui[4], er3=ur[6], ei3=ui[6];
    float fr0=ur[1], fi0=ui[1], fr1=ur[3], fi1=ui[3];
    float fr2=ur[5], fi2=ui[5], fr3=ur[7], fi3=ui[7];
    dft4<SIGN>(er0,ei0, er1,ei1, er2,ei2, er3,ei3);
    dft4<SIGN>(fr0,fi0, fr1,fi1, fr2,fi2, fr3,fi3);
    {   const float c =  h, s_ = (SIGN<0) ? -h : h;
        cmul(fr1, fi1, c, s_); }
    {   float tr = fr2, ti = fi2;
        if (SIGN < 0){ fr2 =  ti; fi2 = -tr; }
        else         { fr2 = -ti; fi2 =  tr; }
    }
    {   const float c = -h, s_ = (SIGN<0) ? -h : h;
        cmul(fr3, fi3, c, s_); }
    ur[0]=er0+fr0; ui[0]=ei0+fi0;
    ur[1]=er1+fr1; ui[1]=ei1+fi1;
    ur[2]=er2+fr2; ui[2]=ei2+fi2;
    ur[3]=er3+fr3; ui[3]=ei3+fi3;
    ur[4]=er0-fr0; ui[4]=ei0-fi0;
    ur[5]=er1-fr1; ui[5]=ei1-fi1;
    ur[6]=er2-fr2; ui[6]=ei2-fi2;
    ur[7]=er3-fr3; ui[7]=ei3-fi3;
}

template<int SIGN>
__device__ __forceinline__ void twiddle8(float ur[8], float ui[8], float theta){
    float s, c;
    __sincosf(theta, &s, &c);
    const float wi = (SIGN < 0) ? -s : s;
    const float wr = c;
    float pr = wr, pi = wi;
    cmul(ur[1], ui[1], pr, pi);
#pragma unroll
    for (int m=2;m<8;m++){
        float nr = pr*wr - pi*wi;
        pi = pr*wi + pi*wr;
        pr = nr;
        cmul(ur[m], ui[m], pr, pi);
    }
}

// gain for spectral index k (0..2048) for BOTH rows at once (shared bg + gathers).
__device__ __forceinline__ void gain_pair(int k, const float* hhA, const float* hhB,
    float alpha, const float* __restrict__ P2w, const float* __restrict__ P2b,
    float& ga, float& gb){
    float nf = (float)k * (1.0f/2048.0f);
    float tt = nf * 5.0f;
    float lb = __expf(-0.5f * tt * tt);
    float hd = 0.5f / (1.0f + __expf(-(nf - 0.6f) * 10.0f));
    float bg = fmaxf(1.0f + lb - hd, 0.0f);
    float scaled = nf * 4095.0f;
    float fl = floorf(scaled);
    int lo = (int)fl;
    int hi = (int)ceilf(scaled);
    float fr = scaled - fl;
    const float4* p2lo = (const float4*)(P2w + (size_t)lo * RANK);
    const float4* p2hi = (const float4*)(P2w + (size_t)hi * RANK);
    float4 a0 = p2lo[0], a1 = p2lo[1];
    float4 b0 = p2hi[0], b1 = p2hi[1];
    float blo = P2b[lo], bhi = P2b[hi];
    float dAlo = blo + hhA[0]*a0.x + hhA[1]*a0.y + hhA[2]*a0.z + hhA[3]*a0.w
                     + hhA[4]*a1.x + hhA[5]*a1.y + hhA[6]*a1.z + hhA[7]*a1.w;
    float dAhi = bhi + hhA[0]*b0.x + hhA[1]*b0.y + hhA[2]*b0.z + hhA[3]*b0.w
                     + hhA[4]*b1.x + hhA[5]*b1.y + hhA[6]*b1.z + hhA[7]*b1.w;
    float dBlo = blo + hhB[0]*a0.x + hhB[1]*a0.y + hhB[2]*a0.z + hhB[3]*a0.w
                     + hhB[4]*a1.x + hhB[5]*a1.y + hhB[6]*a1.z + hhB[7]*a1.w;
    float dBhi = bhi + hhB[0]*b0.x + hhB[1]*b0.y + hhB[2]*b0.z + hhB[3]*b0.w
                     + hhB[4]*b1.x + hhB[5]*b1.y + hhB[6]*b1.z + hhB[7]*b1.w;
    float dA = dAlo + (dAhi - dAlo) * fr;
    float dB = dBlo + (dBhi - dBlo) * fr;
    ga = fmaxf(bg + alpha * dA, 0.0f);
    gb = fmaxf(bg + alpha * dB, 0.0f);
}

// ============================================================================
// REAL-PACKING STRUCTURE (2 rows per block, grid = 1024) — r8/r9, passing.
// r10 change: SPILL FIX = "#pragma unroll 1" on all big outer loops.
//   Evidence: r8 vs r9 had bit-identical scratch traffic (75776 KB WRITE)
//   despite an in-body restructure of do_pair -> pressure comes from the
//   "#pragma unroll" over 4 x gain_pair / 4 x do_pair (4 interleaved ~45-reg
//   bodies >> 64 cap), not from any single body. r4's unpragma'd loops never
//   spilled. Inner r-loops MUST stay fully unrolled (register-array indexing).
// VGPR wall (r2-r7 measured): pool ~256/SIMD; VGPR=64 -> 4 waves/SIMD;
// caps < 64 spill catastrophically. Keep true peak under 64.
// ============================================================================

__global__ __launch_bounds__(NT, 4) void recip_mixer(
    const float* __restrict__ x,
    const float* __restrict__ Ur, const float* __restrict__ Ui,
    const float* __restrict__ Vr, const float* __restrict__ Vi,
    const float* __restrict__ Wr, const float* __restrict__ Wi,
    const float* __restrict__ P1w, const float* __restrict__ P1b,
    const float* __restrict__ P2w, const float* __restrict__ P2b,
    const float* __restrict__ alphap,
    float* __restrict__ out)
{
    __shared__ float sre[BP], sim[BP];
    __shared__ float gA[NHALF], gB[NHALF];
    __shared__ float red[256];
    __shared__ float hidA[RANK], hidB[RANK];
    __shared__ float4 gam4[RANK];   // {gamAr, gamAi, gamBr, gamBi} per r
    __shared__ float pqs[64];

    const int t    = threadIdx.x;
    const int pairidx = blockIdx.x;
    const int lane = t & 63;
    const int wid  = t >> 6;

    float ur[8], ui[8];

    const int baseA = (t & 63) + 512 * (t >> 6);
    const int baseB = (t & 7) + 8*(t >> 6) + 520*((t >> 3) & 7);
    const int baseC = (t >> 3) + 520*(t & 7);

    const float* xa = x + (size_t)(2 * pairidx) * S_LEN;
    const float* xb = xa + S_LEN;

    // ================= forward FFT of w = x_a + i x_b =================
    {
#pragma unroll
        for (int c=0;c<8;c++){ ur[c] = xa[t + 512*c]; ui[c] = xb[t + 512*c]; }
        dft8<-1>(ur, ui);
#pragma unroll
        for (int e=0;e<8;e++){ sre[baseA + 64*e] = ur[e]; sim[baseA + 64*e] = ui[e]; }
    }
    __syncthreads();
    {
#pragma unroll
        for (int m=0;m<8;m++){ ur[m] = sre[t + 512*m]; ui[m] = sim[t + 512*m]; }
        twiddle8<-1>(ur, ui, TWO_PI * (float)(t >> 6) * (1.0f/64.0f));
        dft8<-1>(ur, ui);
        __syncthreads();
#pragma unroll
        for (int e=0;e<8;e++){ sre[baseB + 64*e] = ur[e]; sim[baseB + 64*e] = ui[e]; }
    }
    __syncthreads();
    {
#pragma unroll
        for (int m=0;m<8;m++){ ur[m] = sre[t + 520*m]; ui[m] = sim[t + 520*m]; }
        twiddle8<-1>(ur, ui, TWO_PI * (float)(t >> 3) * (1.0f/512.0f));
        dft8<-1>(ur, ui);
        __syncthreads();
#pragma unroll
        for (int e=0;e<8;e++){ sre[baseC + 64*e] = ur[e]; sim[baseC + 64*e] = ui[e]; }
    }
    __syncthreads();
    {
#pragma unroll
        for (int m=0;m<8;m++){ ur[m] = sre[t + 520*m]; ui[m] = sim[t + 520*m]; }
        twiddle8<-1>(ur, ui, TWO_PI * (float)t * (1.0f/4096.0f));
        dft8<-1>(ur, ui);
        __syncthreads();
#pragma unroll
        for (int e=0;e<8;e++){ sre[t + 512*e] = ur[e]; sim[t + 512*e] = ui[e]; }
    }
    __syncthreads();   // phase 1 reads other threads' (k, N-k) slots

    // ===== phase 1: hidden for BOTH rows (z reconstructed from W on the fly)
    {
        float ha[RANK], hb[RANK];
#pragma unroll
        for (int r = 0; r < RANK; r++){ ha[r] = 0.0f; hb[r] = 0.0f; }
#pragma unroll 1
        for (int i = 0; i < PER; i++) {
            int k = t + NT * i;
            int j = (S_LEN - k) & (S_LEN - 1);
            float ar = sre[k], ai = sim[k];
            float br = sre[j], bi = sim[j];
            float zar = 0.5f*(ar + br), zai = 0.5f*(ai - bi);
            float zbr = 0.5f*(ai + bi), zbi = 0.5f*(br - ar);
#pragma unroll
            for (int r = 0; r < RANK; r++) {
                float p0 = P1w[r * (2 * S_LEN) + k];
                float p1 = P1w[r * (2 * S_LEN) + S_LEN + k];
                ha[r] += zar * p0 + zai * p1;
                hb[r] += zbr * p0 + zbi * p1;
            }
        }
#pragma unroll
        for (int r = 0; r < RANK; r++) {
#pragma unroll
            for (int off = 32; off > 0; off >>= 1){
                ha[r] += __shfl_xor(ha[r], off, 64);
                hb[r] += __shfl_xor(hb[r], off, 64);
            }
        }
        if (lane == 0) {
#pragma unroll
            for (int r = 0; r < RANK; r++){
                red[wid * 16 + r]     = ha[r];
                red[wid * 16 + 8 + r] = hb[r];
            }
        }
        __syncthreads();
        if (t < 16) {
            float v = 0.0f;
#pragma unroll
            for (int w = 0; w < 8; w++) v += red[w * 16 + t];
            float res = fmaxf(v + P1b[t & 7], 0.0f);
            if (t < 8) hidA[t] = res; else hidB[t - 8] = res;
        }
        __syncthreads();
    }

    // ===== phase 2a: half-spectrum gain tables gA/gB[0..2048]
    {
        float hhA[RANK], hhB[RANK];
#pragma unroll
        for (int r = 0; r < RANK; r++){ hhA[r] = hidA[r]; hhB[r] = hidB[r]; }
        const float alpha = alphap[0];
#pragma unroll 1
        for (int i = 0; i < 4; i++) {
            int k = t + 512 * i;           // 0..2047
            float ga, gb;
            gain_pair(k, hhA, hhB, alpha, P2w, P2b, ga, gb);
            gA[k] = ga; gB[k] = gb;
        }
        if (t == 0) {
            float ga, gb;
            gain_pair(2048, hhA, hhB, alpha, P2w, P2b, ga, gb);
            gA[2048] = ga; gB[2048] = gb;
        }
    }
    __syncthreads();   // 2b reads gA/gB at arbitrary m

    // ===== phase 2b p-pass: p for both rows (shared Ur/Ui loads)
    {
        float pAr[RANK], pAi[RANK], pBr[RANK], pBi[RANK];
#pragma unroll
        for (int r = 0; r < RANK; r++){ pAr[r]=0.f; pAi[r]=0.f; pBr[r]=0.f; pBi[r]=0.f; }
#pragma unroll 1
        for (int i = 0; i < PER; i++) {
            int k = t + NT * i;
            int j = (S_LEN - k) & (S_LEN - 1);
            int m = (k <= 2048) ? k : (S_LEN - k);
            float ar = sre[k], ai = sim[k];
            float br = sre[j], bi = sim[j];
            float ga = gA[m], gb = gB[m];
            float zar = 0.5f*ga*(ar + br), zai = 0.5f*ga*(ai - bi);
            float zbr = 0.5f*gb*(ai + bi), zbi = 0.5f*gb*(br - ar);
#pragma unroll
            for (int r = 0; r < RANK; r++) {
                float u_ = Ur[r * S_LEN + k], v_ = Ui[r * S_LEN + k];
                pAr[r] += zar * u_ - zai * v_;
                pAi[r] += zar * v_ + zai * u_;
                pBr[r] += zbr * u_ - zbi * v_;
                pBi[r] += zbr * v_ + zbi * u_;
            }
        }
#pragma unroll
        for (int r = 0; r < RANK; r++) {
#pragma unroll
            for (int off = 32; off > 0; off >>= 1) {
                pAr[r] += __shfl_xor(pAr[r], off, 64);
                pAi[r] += __shfl_xor(pAi[r], off, 64);
                pBr[r] += __shfl_xor(pBr[r], off, 64);
                pBi[r] += __shfl_xor(pBi[r], off, 64);
            }
        }
        if (lane == 0) {
#pragma unroll
            for (int r = 0; r < RANK; r++) {
                red[wid * 32 + r]      = pAr[r];
                red[wid * 32 + 8 + r]  = pAi[r];
                red[wid * 32 + 16 + r] = pBr[r];
                red[wid * 32 + 24 + r] = pBi[r];
            }
        }
        __syncthreads();
        if (t < 32) {
            float v = 0.0f;
#pragma unroll
            for (int w = 0; w < 8; w++) v += red[w * 32 + t];
            pqs[t] = v;
        }
        __syncthreads();
    }

    // ===== phase 2b q-pass: q for both rows (shared Vr/Vi loads), then gamma
    {
        float qAr[RANK], qAi[RANK], qBr[RANK], qBi[RANK];
#pragma unroll
        for (int r = 0; r < RANK; r++){ qAr[r]=0.f; qAi[r]=0.f; qBr[r]=0.f; qBi[r]=0.f; }
#pragma unroll 1
        for (int i = 0; i < PER; i++) {
            int k = t + NT * i;
            int j = (S_LEN - k) & (S_LEN - 1);
            int m = (k <= 2048) ? k : (S_LEN - k);
            float ar = sre[k], ai = sim[k];
            float br = sre[j], bi = sim[j];
            float ga = gA[m], gb = gB[m];
            float zar = 0.5f*ga*(ar + br), zai = 0.5f*ga*(ai - bi);
            float zbr = 0.5f*gb*(ai + bi), zbi = 0.5f*gb*(br - ar);
#pragma unroll
            for (int r = 0; r < RANK; r++) {
                float w_ = Vr[r * S_LEN + k], y_ = Vi[r * S_LEN + k];
                qAr[r] += zar * w_ - zai * y_;
                qAi[r] += zar * y_ + zai * w_;
                qBr[r] += zbr * w_ - zbi * y_;
                qBi[r] += zbr * y_ + zbi * w_;
            }
        }
#pragma unroll
        for (int r = 0; r < RANK; r++) {
#pragma unroll
            for (int off = 32; off > 0; off >>= 1) {
                qAr[r] += __shfl_xor(qAr[r], off, 64);
                qAi[r] += __shfl_xor(qAi[r], off, 64);
                qBr[r] += __shfl_xor(qBr[r], off, 64);
                qBi[r] += __shfl_xor(qBi[r], off, 64);
            }
        }
        if (lane == 0) {
#pragma unroll
            for (int r = 0; r < RANK; r++) {
                red[wid * 32 + r]      = qAr[r];
                red[wid * 32 + 8 + r]  = qAi[r];
                red[wid * 32 + 16 + r] = qBr[r];
                red[wid * 32 + 24 + r] = qBi[r];
            }
        }
        __syncthreads();
        if (t < 32) {
            float v = 0.0f;
#pragma unroll
            for (int w = 0; w < 8; w++) v += red[w * 32 + t];
            pqs[32 + t] = v;
        }
        __syncthreads();
        if (t < 8) {
            float paR = pqs[t],      paI = pqs[8 + t];
            float pbR = pqs[16 + t], pbI = pqs[24 + t];
            float qaR = pqs[32 + t], qaI = pqs[40 + t];
            float qbR = pqs[48 + t], qbI = pqs[56 + t];
            gam4[t] = make_float4(
                paR * qaR + paI * qaI,    // gamAr = Re(p_a conj(q_a))
                paI * qaR - paR * qaI,    // gamAi
                pbR * qbR + pbI * qbI,    // gamBr
                pbI * qbR - pbR * qbI);   // gamBi
        }
        __syncthreads();
    }

    // ===== phase H: z += upd, Hermitian part, pack w2 = H_a + i H_b.
    // Register-lean body + NO outer unroll (one ~45-reg body live at a time).
    {
        auto do_pair = [&](int k){
            int j = (S_LEN - k) & (S_LEN - 1);
            float ar = sre[k], ai = sim[k];
            float br = sre[j], bi = sim[j];
            float ga = gA[k], gb = gB[k];      // k <= 2048 here
            float zar = 0.5f*ga*(ar + br), zai = 0.5f*ga*(ai - bi);
            float zbr = 0.5f*gb*(ai + bi), zbi = 0.5f*gb*(br - ar);

            float uakr=0.f, uaki=0.f, ubkr=0.f, ubki=0.f;
            {
                const float4* WRk = (const float4*)(Wr + (size_t)k * RANK);
                const float4* WIk = (const float4*)(Wi + (size_t)k * RANK);
#pragma unroll
                for (int h2 = 0; h2 < 2; ++h2){
                    float4 w4 = WRk[h2], y4 = WIk[h2];
                    float4 g0 = gam4[4*h2+0];
                    uakr += g0.x*w4.x - g0.y*y4.x;  uaki += g0.x*y4.x + g0.y*w4.x;
                    ubkr += g0.z*w4.x - g0.w*y4.x;  ubki += g0.z*y4.x + g0.w*w4.x;
                    float4 g1 = gam4[4*h2+1];
                    uakr += g1.x*w4.y - g1.y*y4.y;  uaki += g1.x*y4.y + g1.y*w4.y;
                    ubkr += g1.z*w4.y - g1.w*y4.y;  ubki += g1.z*y4.y + g1.w*w4.y;
                    float4 g2 = gam4[4*h2+2];
                    uakr += g2.x*w4.z - g2.y*y4.z;  uaki += g2.x*y4.z + g2.y*w4.z;
                    ubkr += g2.z*w4.z - g2.w*y4.z;  ubki += g2.z*y4.z + g2.w*w4.z;
                    float4 g3 = gam4[4*h2+3];
                    uakr += g3.x*w4.w - g3.y*y4.w;  uaki += g3.x*y4.w + g3.y*w4.w;
                    ubkr += g3.z*w4.w - g3.w*y4.w;  ubki += g3.z*y4.w + g3.w*w4.w;
                }
            }
            float uajr=0.f, uaji=0.f, ubjr=0.f, ubji=0.f;
            {
                const float4* WRj = (const float4*)(Wr + (size_t)j * RANK);
                const float4* WIj = (const float4*)(Wi + (size_t)j * RANK);
#pragma unroll
                for (int h2 = 0; h2 < 2; ++h2){
                    float4 w4 = WRj[h2], y4 = WIj[h2];
                    float4 g0 = gam4[4*h2+0];
                    uajr += g0.x*w4.x - g0.y*y4.x;  uaji += g0.x*y4.x + g0.y*w4.x;
                    ubjr += g0.z*w4.x - g0.w*y4.x;  ubji += g0.z*y4.x + g0.w*w4.x;
                    float4 g1 = gam4[4*h2+1];
                    uajr += g1.x*w4.y - g1.y*y4.y;  uaji += g1.x*y4.y + g1.y*w4.y;
                    ubjr += g1.z*w4.y - g1.w*y4.y;  ubji += g1.z*y4.y + g1.w*w4.y;
                    float4 g2 = gam4[4*h2+2];
                    uajr += g2.x*w4.z - g2.y*y4.z;  uaji += g2.x*y4.z + g2.y*w4.z;
                    ubjr += g2.z*w4.z - g2.w*y4.z;  ubji += g2.z*y4.z + g2.w*w4.z;
                    float4 g3 = gam4[4*h2+3];
                    uajr += g3.x*w4.w - g3.y*y4.w;  uaji += g3.x*y4.w + g3.y*w4.w;
                    ubjr += g3.z*w4.w - g3.w*y4.w;  ubji += g3.z*y4.w + g3.w*w4.w;
                }
            }
            float HaR = zar + 0.5f*(uakr + uajr);
            float HaI = zai + 0.5f*(uaki - uaji);
            float HbR = zbr + 0.5f*(ubkr + ubjr);
            float HbI = zbi + 0.5f*(ubki - ubji);
            sre[k] = HaR - HbI;  sim[k] = HaI + HbR;
            sre[j] = HaR + HbI;  sim[j] = HbR - HaI;
        };
#pragma unroll 1
        for (int i = 0; i < 4; i++) do_pair(t + 512 * i);   // k = 0..2047
        if (t == 0) do_pair(2048);                          // self-pair
    }
    __syncthreads();   // all w2 written before inverse FFT reads

    // ================= inverse FFT: out_a = Re, out_b = Im =================
    {
#pragma unroll
        for (int c=0;c<8;c++){ ur[c] = sre[t + 512*c]; ui[c] = sim[t + 512*c]; }
        dft8<1>(ur, ui);
        __syncthreads();   // w2 consumed before A overwrites
#pragma unroll
        for (int e=0;e<8;e++){ sre[baseA + 64*e] = ur[e]; sim[baseA + 64*e] = ui[e]; }
    }
    __syncthreads();
    {
#pragma unroll
        for (int m=0;m<8;m++){ ur[m] = sre[t + 512*m]; ui[m] = sim[t + 512*m]; }
        twiddle8<1>(ur, ui, TWO_PI * (float)(t >> 6) * (1.0f/64.0f));
        dft8<1>(ur, ui);
        __syncthreads();
#pragma unroll
        for (int e=0;e<8;e++){ sre[baseB + 64*e] = ur[e]; sim[baseB + 64*e] = ui[e]; }
    }
    __syncthreads();
    {
#pragma unroll
        for (int m=0;m<8;m++){ ur[m] = sre[t + 520*m]; ui[m] = sim[t + 520*m]; }
        twiddle8<1>(ur, ui, TWO_PI * (float)(t >> 3) * (1.0f/512.0f));
        dft8<1>(ur, ui);
        __syncthreads();
#pragma unroll
        for (int e=0;e<8;e++){ sre[baseC + 64*e] = ur[e]; sim[baseC + 64*e] = ui[e]; }
    }
    __syncthreads();
    {
#pragma unroll
        for (int m=0;m<8;m++){ ur[m] = sre[t + 520*m]; ui[m] = sim[t + 520*m]; }
        twiddle8<1>(ur, ui, TWO_PI * (float)t * (1.0f/4096.0f));
        dft8<1>(ur, ui);
        float* orow_a = out + (size_t)(2 * pairidx) * S_LEN;
        float* orow_b = orow_a + S_LEN;
        const float scale = 1.0f / (float)S_LEN;
#pragma unroll
        for (int e=0;e<8;e++){
            orow_a[t + 512*e] = ur[e] * scale;   // Re -> row a
            orow_b[t + 512*e] = ui[e] * scale;   // Im -> row b
        }
    }
}

extern "C" void kernel_launch(void* const* d_in, const int* in_sizes, int n_in,
                              void* d_out, int out_size, void* d_ws, size_t ws_size,
                              hipStream_t stream) {
    const float* x    = (const float*)d_in[0];
    const float* Ur   = (const float*)d_in[1];
    const float* Ui   = (const float*)d_in[2];
    const float* Vr   = (const float*)d_in[3];
    const float* Vi   = (const float*)d_in[4];
    const float* Wr   = (const float*)d_in[5];
    const float* Wi   = (const float*)d_in[6];
    const float* P1w  = (const float*)d_in[7];
    const float* P1b  = (const float*)d_in[8];
    const float* P2w  = (const float*)d_in[9];
    const float* P2b  = (const float*)d_in[10];
    const float* alph = (const float*)d_in[11];

    recip_mixer<<<dim3(1024), dim3(NT), 0, stream>>>(
        x, Ur, Ui, Vr, Vi, Wr, Wi, P1w, P1b, P2w, P2b, alph, (float*)d_out);
}

// Round 11
// 184.899 us; speedup vs baseline: 1.8521x; 1.0459x over previous
//
#include <hip/hip_runtime.h>

#define S_LEN 4096
#define NT 512
#define PER 8
#define RANK 8
#define BP 4160      // padded FFT buffer float count (max transpose addr 4151)
#define NHALF 2049   // half-spectrum gain table (k = 0..2048)
#define TWO_PI 6.2831853071795864769f

__device__ __forceinline__ void cmul(float& xr, float& xi, float cr, float ci){
    float tr = xr*cr - xi*ci;
    xi = xr*ci + xi*cr;
    xr = tr;
}

// 4-point DFT, in place. SIGN=-1 forward, SIGN=+1 inverse.
template<int SIGN>
__device__ __forceinline__ void dft4(float& ar,float& ai,float& br,float& bi,
                                     float& cr,float& ci,float& dr,float& di){
    float Ar=ar+cr, Ai=ai+ci;
    float Br=ar-cr, Bi=ai-ci;
    float Cr=br+dr, Ci=bi+di;
    float Dr, Di;
    if (SIGN < 0){ Dr = bi-di; Di = dr-br; }
    else         { Dr = di-bi; Di = br-dr; }
    ar=Ar+Cr; ai=Ai+Ci;
    br=Br+Dr; bi=Bi+Di;
    cr=Ar-Cr; ci=Ai-Ci;
    dr=Br-Dr; di=Bi-Di;
}

// 8-point DFT in registers, natural-order in and out.
template<int SIGN>
__device__ __forceinline__ void dft8(float ur[8], float ui[8]){
    const float h = 0.70710678118654752f;
    float er0=ur[0], ei0=ui[0], er1=ur[2], ei1=ui[2];
    float er2=ur[4], ei2=ui[4], er3=ur[6], ei3=ui[6];
    float fr0=ur[1], fi0=ui[1], fr1=ur[3], fi1=ui[3];
    float fr2=ur[5], fi2=ui[5], fr3=ur[7], fi3=ui[7];
    dft4<SIGN>(er0,ei0, er1,ei1, er2,ei2, er3,ei3);
    dft4<SIGN>(fr0,fi0, fr1,fi1, fr2,fi2, fr3,fi3);
    {   const float c =  h, s_ = (SIGN<0) ? -h : h;
        cmul(fr1, fi1, c, s_); }
    {   float tr = fr2, ti = fi2;
        if (SIGN < 0){ fr2 =  ti; fi2 = -tr; }
        else         { fr2 = -ti; fi2 =  tr; }
    }
    {   const float c = -h, s_ = (SIGN<0) ? -h : h;
        cmul(fr3, fi3, c, s_); }
    ur[0]=er0+fr0; ui[0]=ei0+fi0;
    ur[1]=er1+fr1; ui[1]=ei1+fi1;
    ur[2]=er2+fr2; ui[2]=ei2+fi2;
    ur[3]=er3+fr3; ui[3]=ei3+fi3;
    ur[4]=er0-fr0; ui[4]=ei0-fi0;
    ur[5]=er1-fr1; ui[5]=ei1-fi1;
    ur[6]=er2-fr2; ui[6]=ei2-fi2;
    ur[7]=er3-fr3; ui[7]=ei3-fi3;
}

// balanced-tree twiddle powers (dep depth 3 vs 7 serial) + apply
template<int SIGN>
__device__ __forceinline__ void twiddle8(float ur[8], float ui[8], float theta){
    float s, c;
    __sincosf(theta, &s, &c);
    const float w1i = (SIGN < 0) ? -s : s;
    const float w1r = c;
    float w2r = w1r*w1r - w1i*w1i, w2i = 2.0f*w1r*w1i;
    float w3r = w2r*w1r - w2i*w1i, w3i = w2r*w1i + w2i*w1r;
    float w4r = w2r*w2r - w2i*w2i, w4i = 2.0f*w2r*w2i;
    float w5r = w4r*w1r - w4i*w1i, w5i = w4r*w1i + w4i*w1r;
    float w6r = w3r*w3r - w3i*w3i, w6i = 2.0f*w3r*w3i;
    float w7r = w4r*w3r - w4i*w3i, w7i = w4r*w3i + w4i*w3r;
    cmul(ur[1], ui[1], w1r, w1i);
    cmul(ur[2], ui[2], w2r, w2i);
    cmul(ur[3], ui[3], w3r, w3i);
    cmul(ur[4], ui[4], w4r, w4i);
    cmul(ur[5], ui[5], w5r, w5i);
    cmul(ur[6], ui[6], w6r, w6i);
    cmul(ur[7], ui[7], w7r, w7i);
}

// gain for spectral index k (0..2048) for BOTH rows at once (shared bg + gathers).
__device__ __forceinline__ void gain_pair(int k, const float* hhA, const float* hhB,
    float alpha, const float* __restrict__ P2w, const float* __restrict__ P2b,
    float& ga, float& gb){
    float nf = (float)k * (1.0f/2048.0f);
    float tt = nf * 5.0f;
    float lb = __expf(-0.5f * tt * tt);
    float hd = 0.5f / (1.0f + __expf(-(nf - 0.6f) * 10.0f));
    float bg = fmaxf(1.0f + lb - hd, 0.0f);
    float scaled = nf * 4095.0f;
    float fl = floorf(scaled);
    int lo = (int)fl;
    int hi = (int)ceilf(scaled);
    float fr = scaled - fl;
    const float4* p2lo = (const float4*)(P2w + (size_t)lo * RANK);
    const float4* p2hi = (const float4*)(P2w + (size_t)hi * RANK);
    float4 a0 = p2lo[0], a1 = p2lo[1];
    float4 b0 = p2hi[0], b1 = p2hi[1];
    float blo = P2b[lo], bhi = P2b[hi];
    float dAlo = blo + hhA[0]*a0.x + hhA[1]*a0.y + hhA[2]*a0.z + hhA[3]*a0.w
                     + hhA[4]*a1.x + hhA[5]*a1.y + hhA[6]*a1.z + hhA[7]*a1.w;
    float dAhi = bhi + hhA[0]*b0.x + hhA[1]*b0.y + hhA[2]*b0.z + hhA[3]*b0.w
                     + hhA[4]*b1.x + hhA[5]*b1.y + hhA[6]*b1.z + hhA[7]*b1.w;
    float dBlo = blo + hhB[0]*a0.x + hhB[1]*a0.y + hhB[2]*a0.z + hhB[3]*a0.w
                     + hhB[4]*a1.x + hhB[5]*a1.y + hhB[6]*a1.z + hhB[7]*a1.w;
    float dBhi = bhi + hhB[0]*b0.x + hhB[1]*b0.y + hhB[2]*b0.z + hhB[3]*b0.w
                     + hhB[4]*b1.x + hhB[5]*b1.y + hhB[6]*b1.z + hhB[7]*b1.w;
    float dA = dAlo + (dAhi - dAlo) * fr;
    float dB = dBlo + (dBhi - dBlo) * fr;
    ga = fmaxf(bg + alpha * dA, 0.0f);
    gb = fmaxf(bg + alpha * dB, 0.0f);
}

// ============================================================================
// REAL-PACKING (2 rows/block, grid 1024) + PAIR-BASED middle phases.
// r11: each thread owns 4 Hermitian pairs (k=t+512i, j=4096-k). Phase1 and
// p/q passes fold Term(k)+Term(j) via shared weight sums:
//   Re: zar*(uk+uj) - zai*(vk-vj); Im: zar*(vk+vj) + zai*(uk-uj)
// (25% fewer FMA, half the recon/gain/z LDS traffic). Self-pairs k=0/2048:
// jm mask folded into fmaf (k=0), t0 tail iteration (k=2048).
// Gains gA/gB[k] are written and read by the SAME thread -> 2a barrier gone.
// p/q stay SPLIT (32 accum each): merged pass risks the 64-reg wall.
// Unroll discipline (r10 lesson): "#pragma unroll 1" on ALL big outer loops —
// interleaved ~45-reg bodies are what spilled r5-r9; bodies were never the
// problem. Inner r-loops fully unrolled (register arrays, rule #20).
// VGPR wall (r2-r7): pool ~256/SIMD; 64 -> 4 waves/SIMD; <64 cap spills.
// Occupancy hard-walled at 2 blocks/CU; lever is instruction count.
// ============================================================================

__global__ __launch_bounds__(NT, 4) void recip_mixer(
    const float* __restrict__ x,
    const float* __restrict__ Ur, const float* __restrict__ Ui,
    const float* __restrict__ Vr, const float* __restrict__ Vi,
    const float* __restrict__ Wr, const float* __restrict__ Wi,
    const float* __restrict__ P1w, const float* __restrict__ P1b,
    const float* __restrict__ P2w, const float* __restrict__ P2b,
    const float* __restrict__ alphap,
    float* __restrict__ out)
{
    __shared__ float sre[BP], sim[BP];
    __shared__ float gA[NHALF], gB[NHALF];
    __shared__ float red[256];
    __shared__ float hidA[RANK], hidB[RANK];
    __shared__ float4 gam4[RANK];   // {gamAr, gamAi, gamBr, gamBi} per r
    __shared__ float pqs[64];

    const int t    = threadIdx.x;
    const int pairidx = blockIdx.x;
    const int lane = t & 63;
    const int wid  = t >> 6;

    float ur[8], ui[8];

    const int baseA = (t & 63) + 512 * (t >> 6);
    const int baseB = (t & 7) + 8*(t >> 6) + 520*((t >> 3) & 7);
    const int baseC = (t >> 3) + 520*(t & 7);

    const float* xa = x + (size_t)(2 * pairidx) * S_LEN;
    const float* xb = xa + S_LEN;

    // ================= forward FFT of w = x_a + i x_b =================
    {
#pragma unroll
        for (int c=0;c<8;c++){ ur[c] = xa[t + 512*c]; ui[c] = xb[t + 512*c]; }
        dft8<-1>(ur, ui);
#pragma unroll
        for (int e=0;e<8;e++){ sre[baseA + 64*e] = ur[e]; sim[baseA + 64*e] = ui[e]; }
    }
    __syncthreads();
    {
#pragma unroll
        for (int m=0;m<8;m++){ ur[m] = sre[t + 512*m]; ui[m] = sim[t + 512*m]; }
        twiddle8<-1>(ur, ui, TWO_PI * (float)(t >> 6) * (1.0f/64.0f));
        dft8<-1>(ur, ui);
        __syncthreads();
#pragma unroll
        for (int e=0;e<8;e++){ sre[baseB + 64*e] = ur[e]; sim[baseB + 64*e] = ui[e]; }
    }
    __syncthreads();
    {
#pragma unroll
        for (int m=0;m<8;m++){ ur[m] = sre[t + 520*m]; ui[m] = sim[t + 520*m]; }
        twiddle8<-1>(ur, ui, TWO_PI * (float)(t >> 3) * (1.0f/512.0f));
        dft8<-1>(ur, ui);
        __syncthreads();
#pragma unroll
        for (int e=0;e<8;e++){ sre[baseC + 64*e] = ur[e]; sim[baseC + 64*e] = ui[e]; }
    }
    __syncthreads();
    {
#pragma unroll
        for (int m=0;m<8;m++){ ur[m] = sre[t + 520*m]; ui[m] = sim[t + 520*m]; }
        twiddle8<-1>(ur, ui, TWO_PI * (float)t * (1.0f/4096.0f));
        dft8<-1>(ur, ui);
        __syncthreads();
#pragma unroll
        for (int e=0;e<8;e++){ sre[t + 512*e] = ur[e]; sim[t + 512*e] = ui[e]; }
    }
    __syncthreads();   // middle phases read other threads' (k, N-k) slots

    // ===== phase 1: hidden for BOTH rows — pair-based (4 pairs/thread)
    {
        float ha[RANK], hb[RANK];
#pragma unroll
        for (int r = 0; r < RANK; r++){ ha[r] = 0.0f; hb[r] = 0.0f; }
#pragma unroll 1
        for (int i = 0; i < 4; i++) {
            int k = t + 512 * i;
            int j = (S_LEN - k) & (S_LEN - 1);
            float jm = (k == 0) ? 0.0f : 1.0f;   // kill j-side weights for self-pair
            float ar = sre[k], ai = sim[k];
            float br = sre[j], bi = sim[j];
            float zar = 0.5f*(ar + br), zai = 0.5f*(ai - bi);
            float zbr = 0.5f*(ai + bi), zbi = 0.5f*(br - ar);
#pragma unroll
            for (int r = 0; r < RANK; r++) {
                const float* P1r = P1w + r * (2 * S_LEN);
                float p0k = P1r[k],        p1k = P1r[S_LEN + k];
                float p0j = P1r[j],        p1j = P1r[S_LEN + j];
                float us = fmaf(jm, p0j, p0k);    // p0k + p0j
                float ud = fmaf(-jm, p1j, p1k);   // p1k - p1j
                ha[r] += zar * us + zai * ud;
                hb[r] += zbr * us + zbi * ud;
            }
        }
        if (t == 0) {
            // self-pair k = 2048: za = Re W (zai=0), zb = Im W (zbi=0)
            float ar = sre[2048], ai = sim[2048];
#pragma unroll
            for (int r = 0; r < RANK; r++) {
                float p0 = P1w[r * (2 * S_LEN) + 2048];
                ha[r] += ar * p0;
                hb[r] += ai * p0;
            }
        }
#pragma unroll
        for (int r = 0; r < RANK; r++) {
#pragma unroll
            for (int off = 32; off > 0; off >>= 1){
                ha[r] += __shfl_xor(ha[r], off, 64);
                hb[r] += __shfl_xor(hb[r], off, 64);
            }
        }
        if (lane == 0) {
#pragma unroll
            for (int r = 0; r < RANK; r++){
                red[wid * 16 + r]     = ha[r];
                red[wid * 16 + 8 + r] = hb[r];
            }
        }
        __syncthreads();
        if (t < 16) {
            float v = 0.0f;
#pragma unroll
            for (int w = 0; w < 8; w++) v += red[w * 16 + t];
            float res = fmaxf(v + P1b[t & 7], 0.0f);
            if (t < 8) hidA[t] = res; else hidB[t - 8] = res;
        }
        __syncthreads();
    }

    // ===== phase 2a: half-spectrum gain tables gA/gB[0..2048]
    // (each thread writes only its own k set {t+512i} (+2048 by t0); all later
    //  reads are by the SAME thread -> no barrier needed after this phase)
    {
        float hhA[RANK], hhB[RANK];
#pragma unroll
        for (int r = 0; r < RANK; r++){ hhA[r] = hidA[r]; hhB[r] = hidB[r]; }
        const float alpha = alphap[0];
#pragma unroll 1
        for (int i = 0; i < 4; i++) {
            int k = t + 512 * i;           // 0..2047
            float ga, gb;
            gain_pair(k, hhA, hhB, alpha, P2w, P2b, ga, gb);
            gA[k] = ga; gB[k] = gb;
        }
        if (t == 0) {
            float ga, gb;
            gain_pair(2048, hhA, hhB, alpha, P2w, P2b, ga, gb);
            gA[2048] = ga; gB[2048] = gb;
        }
    }
    // no __syncthreads: own-slot gain reads only from here on

    // ===== phase 2b p-pass: pair-based (4 pairs/thread), rows A+B
    {
        float pAr[RANK], pAi[RANK], pBr[RANK], pBi[RANK];
#pragma unroll
        for (int r = 0; r < RANK; r++){ pAr[r]=0.f; pAi[r]=0.f; pBr[r]=0.f; pBi[r]=0.f; }
#pragma unroll 1
        for (int i = 0; i < 4; i++) {
            int k = t + 512 * i;
            int j = (S_LEN - k) & (S_LEN - 1);
            float jm = (k == 0) ? 0.0f : 1.0f;
            float ar = sre[k], ai = sim[k];
            float br = sre[j], bi = sim[j];
            float ga = gA[k], gb = gB[k];
            float zar = 0.5f*ga*(ar + br), zai = 0.5f*ga*(ai - bi);
            float zbr = 0.5f*gb*(ai + bi), zbi = 0.5f*gb*(br - ar);
#pragma unroll
            for (int r = 0; r < RANK; r++) {
                const float* Urr = Ur + r * S_LEN;
                const float* Uir = Ui + r * S_LEN;
                float ukr = Urr[k], uki = Uir[k];
                float ujr = Urr[j], uji = Uir[j];
                float us = fmaf(jm, ujr, ukr);    // ukr + ujr
                float ud = fmaf(-jm, ujr, ukr);   // ukr - ujr
                float vs = fmaf(jm, uji, uki);    // uki + uji
                float vd = fmaf(-jm, uji, uki);   // uki - uji
                pAr[r] += zar * us - zai * vd;
                pAi[r] += zar * vs + zai * ud;
                pBr[r] += zbr * us - zbi * vd;
                pBi[r] += zbr * vs + zbi * ud;
            }
        }
        if (t == 0) {
            float ar = sre[2048], ai = sim[2048];
            float zar = gA[2048] * ar;   // zai = 0
            float zbr = gB[2048] * ai;   // zbi = 0
#pragma unroll
            for (int r = 0; r < RANK; r++) {
                float ukr = Ur[r * S_LEN + 2048], uki = Ui[r * S_LEN + 2048];
                pAr[r] += zar * ukr;  pAi[r] += zar * uki;
                pBr[r] += zbr * ukr;  pBi[r] += zbr * uki;
            }
        }
#pragma unroll
        for (int r = 0; r < RANK; r++) {
#pragma unroll
            for (int off = 32; off > 0; off >>= 1) {
                pAr[r] += __shfl_xor(pAr[r], off, 64);
                pAi[r] += __shfl_xor(pAi[r], off, 64);
                pBr[r] += __shfl_xor(pBr[r], off, 64);
                pBi[r] += __shfl_xor(pBi[r], off, 64);
            }
        }
        if (lane == 0) {
#pragma unroll
            for (int r = 0; r < RANK; r++) {
                red[wid * 32 + r]      = pAr[r];
                red[wid * 32 + 8 + r]  = pAi[r];
                red[wid * 32 + 16 + r] = pBr[r];
                red[wid * 32 + 24 + r] = pBi[r];
            }
        }
        __syncthreads();
        if (t < 32) {
            float v = 0.0f;
#pragma unroll
            for (int w = 0; w < 8; w++) v += red[w * 32 + t];
            pqs[t] = v;
        }
        __syncthreads();
    }

    // ===== phase 2b q-pass: pair-based, rows A+B, then gamma
    {
        float qAr[RANK], qAi[RANK], qBr[RANK], qBi[RANK];
#pragma unroll
        for (int r = 0; r < RANK; r++){ qAr[r]=0.f; qAi[r]=0.f; qBr[r]=0.f; qBi[r]=0.f; }
#pragma unroll 1
        for (int i = 0; i < 4; i++) {
            int k = t + 512 * i;
            int j = (S_LEN - k) & (S_LEN - 1);
            float jm = (k == 0) ? 0.0f : 1.0f;
            float ar = sre[k], ai = sim[k];
            float br = sre[j], bi = sim[j];
            float ga = gA[k], gb = gB[k];
            float zar = 0.5f*ga*(ar + br), zai = 0.5f*ga*(ai - bi);
            float zbr = 0.5f*gb*(ai + bi), zbi = 0.5f*gb*(br - ar);
#pragma unroll
            for (int r = 0; r < RANK; r++) {
                const float* Vrr = Vr + r * S_LEN;
                const float* Vir = Vi + r * S_LEN;
                float wkr = Vrr[k], wki = Vir[k];
                float wjr = Vrr[j], wji = Vir[j];
                float us = fmaf(jm, wjr, wkr);
                float ud = fmaf(-jm, wjr, wkr);
                float vs = fmaf(jm, wji, wki);
                float vd = fmaf(-jm, wji, wki);
                qAr[r] += zar * us - zai * vd;
                qAi[r] += zar * vs + zai * ud;
                qBr[r] += zbr * us - zbi * vd;
                qBi[r] += zbr * vs + zbi * ud;
            }
        }
        if (t == 0) {
            float ar = sre[2048], ai = sim[2048];
            float zar = gA[2048] * ar;   // zai = 0
            float zbr = gB[2048] * ai;   // zbi = 0
#pragma unroll
            for (int r = 0; r < RANK; r++) {
                float wkr = Vr[r * S_LEN + 2048], wki = Vi[r * S_LEN + 2048];
                qAr[r] += zar * wkr;  qAi[r] += zar * wki;
                qBr[r] += zbr * wkr;  qBi[r] += zbr * wki;
            }
        }
#pragma unroll
        for (int r = 0; r < RANK; r++) {
#pragma unroll
            for (int off = 32; off > 0; off >>= 1) {
                qAr[r] += __shfl_xor(qAr[r], off, 64);
                qAi[r] += __shfl_xor(qAi[r], off, 64);
                qBr[r] += __shfl_xor(qBr[r], off, 64);
                qBi[r] += __shfl_xor(qBi[r], off, 64);
            }
        }
        if (lane == 0) {
#pragma unroll
            for (int r = 0; r < RANK; r++) {
                red[wid * 32 + r]      = qAr[r];
                red[wid * 32 + 8 + r]  = qAi[r];
                red[wid * 32 + 16 + r] = qBr[r];
                red[wid * 32 + 24 + r] = qBi[r];
            }
        }
        __syncthreads();
        if (t < 32) {
            float v = 0.0f;
#pragma unroll
            for (int w = 0; w < 8; w++) v += red[w * 32 + t];
            pqs[32 + t] = v;
        }
        __syncthreads();
        if (t < 8) {
            float paR = pqs[t],      paI = pqs[8 + t];
            float pbR = pqs[16 + t], pbI = pqs[24 + t];
            float qaR = pqs[32 + t], qaI = pqs[40 + t];
            float qbR = pqs[48 + t], qbI = pqs[56 + t];
            gam4[t] = make_float4(
                paR * qaR + paI * qaI,    // gamAr = Re(p_a conj(q_a))
                paI * qaR - paR * qaI,    // gamAi
                pbR * qbR + pbI * qbI,    // gamBr
                pbI * qbR - pbR * qbI);   // gamBi
        }
        __syncthreads();
    }

    // ===== phase H: z += upd, Hermitian part, pack w2 = H_a + i H_b.
    // Register-lean body + NO outer unroll (one ~45-reg body live at a time).
    {
        auto do_pair = [&](int k){
            int j = (S_LEN - k) & (S_LEN - 1);
            float ar = sre[k], ai = sim[k];
            float br = sre[j], bi = sim[j];
            float ga = gA[k], gb = gB[k];      // own-slot (written in 2a by this thread)
            float zar = 0.5f*ga*(ar + br), zai = 0.5f*ga*(ai - bi);
            float zbr = 0.5f*gb*(ai + bi), zbi = 0.5f*gb*(br - ar);

            float uakr=0.f, uaki=0.f, ubkr=0.f, ubki=0.f;
            {
                const float4* WRk = (const float4*)(Wr + (size_t)k * RANK);
                const float4* WIk = (const float4*)(Wi + (size_t)k * RANK);
#pragma unroll
                for (int h2 = 0; h2 < 2; ++h2){
                    float4 w4 = WRk[h2], y4 = WIk[h2];
                    float4 g0 = gam4[4*h2+0];
                    uakr += g0.x*w4.x - g0.y*y4.x;  uaki += g0.x*y4.x + g0.y*w4.x;
                    ubkr += g0.z*w4.x - g0.w*y4.x;  ubki += g0.z*y4.x + g0.w*w4.x;
                    float4 g1 = gam4[4*h2+1];
                    uakr += g1.x*w4.y - g1.y*y4.y;  uaki += g1.x*y4.y + g1.y*w4.y;
                    ubkr += g1.z*w4.y - g1.w*y4.y;  ubki += g1.z*y4.y + g1.w*w4.y;
                    float4 g2 = gam4[4*h2+2];
                    uakr += g2.x*w4.z - g2.y*y4.z;  uaki += g2.x*y4.z + g2.y*w4.z;
                    ubkr += g2.z*w4.z - g2.w*y4.z;  ubki += g2.z*y4.z + g2.w*w4.z;
                    float4 g3 = gam4[4*h2+3];
                    uakr += g3.x*w4.w - g3.y*y4.w;  uaki += g3.x*y4.w + g3.y*w4.w;
                    ubkr += g3.z*w4.w - g3.w*y4.w;  ubki += g3.z*y4.w + g3.w*w4.w;
                }
            }
            float uajr=0.f, uaji=0.f, ubjr=0.f, ubji=0.f;
            {
                const float4* WRj = (const float4*)(Wr + (size_t)j * RANK);
                const float4* WIj = (const float4*)(Wi + (size_t)j * RANK);
#pragma unroll
                for (int h2 = 0; h2 < 2; ++h2){
                    float4 w4 = WRj[h2], y4 = WIj[h2];
                    float4 g0 = gam4[4*h2+0];
                    uajr += g0.x*w4.x - g0.y*y4.x;  uaji += g0.x*y4.x + g0.y*w4.x;
                    ubjr += g0.z*w4.x - g0.w*y4.x;  ubji += g0.z*y4.x + g0.w*w4.x;
                    float4 g1 = gam4[4*h2+1];
                    uajr += g1.x*w4.y - g1.y*y4.y;  uaji += g1.x*y4.y + g1.y*w4.y;
                    ubjr += g1.z*w4.y - g1.w*y4.y;  ubji += g1.z*y4.y + g1.w*w4.y;
                    float4 g2 = gam4[4*h2+2];
                    uajr += g2.x*w4.z - g2.y*y4.z;  uaji += g2.x*y4.z + g2.y*w4.z;
                    ubjr += g2.z*w4.z - g2.w*y4.z;  ubji += g2.z*y4.z + g2.w*w4.z;
                    float4 g3 = gam4[4*h2+3];
                    uajr += g3.x*w4.w - g3.y*y4.w;  uaji += g3.x*y4.w + g3.y*w4.w;
                    ubjr += g3.z*w4.w - g3.w*y4.w;  ubji += g3.z*y4.w + g3.w*w4.w;
                }
            }
            float HaR = zar + 0.5f*(uakr + uajr);
            float HaI = zai + 0.5f*(uaki - uaji);
            float HbR = zbr + 0.5f*(ubkr + ubjr);
            float HbI = zbi + 0.5f*(ubki - ubji);
            sre[k] = HaR - HbI;  sim[k] = HaI + HbR;
            sre[j] = HaR + HbI;  sim[j] = HbR - HaI;
        };
#pragma unroll 1
        for (int i = 0; i < 4; i++) do_pair(t + 512 * i);   // k = 0..2047
        if (t == 0) do_pair(2048);                          // self-pair
    }
    __syncthreads();   // all w2 written before inverse FFT reads

    // ================= inverse FFT: out_a = Re, out_b = Im =================
    {
#pragma unroll
        for (int c=0;c<8;c++){ ur[c] = sre[t + 512*c]; ui[c] = sim[t + 512*c]; }
        dft8<1>(ur, ui);
        __syncthreads();   // w2 consumed before A overwrites
#pragma unroll
        for (int e=0;e<8;e++){ sre[baseA + 64*e] = ur[e]; sim[baseA + 64*e] = ui[e]; }
    }
    __syncthreads();
    {
#pragma unroll
        for (int m=0;m<8;m++){ ur[m] = sre[t + 512*m]; ui[m] = sim[t + 512*m]; }
        twiddle8<1>(ur, ui, TWO_PI * (float)(t >> 6) * (1.0f/64.0f));
        dft8<1>(ur, ui);
        __syncthreads();
#pragma unroll
        for (int e=0;e<8;e++){ sre[baseB + 64*e] = ur[e]; sim[baseB + 64*e] = ui[e]; }
    }
    __syncthreads();
    {
#pragma unroll
        for (int m=0;m<8;m++){ ur[m] = sre[t + 520*m]; ui[m] = sim[t + 520*m]; }
        twiddle8<1>(ur, ui, TWO_PI * (float)(t >> 3) * (1.0f/512.0f));
        dft8<1>(ur, ui);
        __syncthreads();
#pragma unroll
        for (int e=0;e<8;e++){ sre[baseC + 64*e] = ur[e]; sim[baseC + 64*e] = ui[e]; }
    }
    __syncthreads();
    {
#pragma unroll
        for (int m=0;m<8;m++){ ur[m] = sre[t + 520*m]; ui[m] = sim[t + 520*m]; }
        twiddle8<1>(ur, ui, TWO_PI * (float)t * (1.0f/4096.0f));
        dft8<1>(ur, ui);
        float* orow_a = out + (size_t)(2 * pairidx) * S_LEN;
        float* orow_b = orow_a + S_LEN;
        const float scale = 1.0f / (float)S_LEN;
#pragma unroll
        for (int e=0;e<8;e++){
            orow_a[t + 512*e] = ur[e] * scale;   // Re -> row a
            orow_b[t + 512*e] = ui[e] * scale;   // Im -> row b
        }
    }
}

extern "C" void kernel_launch(void* const* d_in, const int* in_sizes, int n_in,
                              void* d_out, int out_size, void* d_ws, size_t ws_size,
                              hipStream_t stream) {
    const float* x    = (const float*)d_in[0];
    const float* Ur   = (const float*)d_in[1];
    const float* Ui   = (const float*)d_in[2];
    const float* Vr   = (const float*)d_in[3];
    const float* Vi   = (const float*)d_in[4];
    const float* Wr   = (const float*)d_in[5];
    const float* Wi   = (const float*)d_in[6];
    const float* P1w  = (const float*)d_in[7];
    const float* P1b  = (const float*)d_in[8];
    const float* P2w  = (const float*)d_in[9];
    const float* P2b  = (const float*)d_in[10];
    const float* alph = (const float*)d_in[11];

    recip_mixer<<<dim3(1024), dim3(NT), 0, stream>>>(
        x, Ur, Ui, Vr, Vi, Wr, Wi, P1w, P1b, P2w, P2b, alph, (float*)d_out);
}